// Round 1
// baseline (355.715 us; speedup 1.0000x reference)
//
#include <hip/hip_runtime.h>

#define NROWS 16384   // B*L
#define LSEQ  2048
#define NB    8

typedef short v8s __attribute__((ext_vector_type(8)));
typedef float v4f __attribute__((ext_vector_type(4)));

__device__ __forceinline__ unsigned short f2bf(float f) {
    unsigned int u = __float_as_uint(f);
    return (unsigned short)((u + 0x7fffu + ((u >> 16) & 1u)) >> 16);
}
__device__ __forceinline__ float bf2f(unsigned short u) {
    return __uint_as_float(((unsigned int)u) << 16);
}

// async global->LDS, 16B per lane; LDS dest is wave-uniform base + lane*16
__device__ __forceinline__ void glds16(const void* g, void* l) {
    __builtin_amdgcn_global_load_lds(
        (__attribute__((address_space(1))) void*)g,
        (__attribute__((address_space(3))) void*)l,
        16, 0, 0);
}

// fast exact-GELU: Abramowitz-Stegun 5-term erf, |err|<1.5e-7
__device__ __forceinline__ float fast_gelu(float v) {
    float z = fabsf(v) * 0.70710678118654752f;
    float t = __builtin_amdgcn_rcpf(1.0f + 0.3275911f * z);
    float poly = t * (0.254829592f + t * (-0.284496736f + t * (1.421413741f +
                 t * (-1.453152027f + t * 1.061405429f))));
    float erfz = 1.0f - poly * __expf(-z * z);
    float er = copysignf(erfz, v);
    return 0.5f * v * (1.0f + er);
}
__device__ __forceinline__ float fast_tanh(float y) {
    float e = __expf(2.0f * y);
    return (e - 1.0f) * __builtin_amdgcn_rcpf(e + 1.0f);
}

// XCD row-swizzle: block b (of 4096, 4 rows each) -> rows of 128-row tile T with
// T%8 == b%8, so the producer's XCD matches the GEMM reader's XCD (= (m>>7)%8).
__device__ __forceinline__ long swizzled_row(int b, int wave) {
    int T = (b & 7) + (((b >> 3) & 15) << 3);   // 0..127, T%8 == b%8
    int chunk = b >> 7;                          // 0..31
    return (long)T * 128 + chunk * 4 + wave;
}

// ------- merged setup: embed (blocks 0..4095, XCD-swizzled) | weight transposes
//         (4096..6239) | class converts (6240..6242); embed also emits LN0(hl) -------
__global__ __launch_bounds__(256) void setup_kernel(
        const int* __restrict__ ids,
        const float* __restrict__ tok, const float* __restrict__ pos,
        const float* __restrict__ g0, const float* __restrict__ b0,
        unsigned short* __restrict__ x, unsigned short* __restrict__ hl,
        const float* __restrict__ w1, const float* __restrict__ w2,
        const float* __restrict__ wa, const float* __restrict__ wb, const float* __restrict__ wc,
        const float* __restrict__ ca, const float* __restrict__ cb, const float* __restrict__ cc,
        unsigned short* __restrict__ w1T, unsigned short* __restrict__ w2T,
        unsigned short* __restrict__ wabcT, unsigned short* __restrict__ clsb) {
    int blk = blockIdx.x;
    int t = threadIdx.x;
    if (blk < 4096) {
        int wave = t >> 6, lane = t & 63;
        long row = swizzled_row(blk, wave);
        int l = (int)(row & (LSEQ - 1));
        int id = ids[row];
        int d = lane * 8;
        float4 t0 = *(const float4*)(tok + (size_t)id * 512 + d);
        float4 t1 = *(const float4*)(tok + (size_t)id * 512 + d + 4);
        float4 p0 = *(const float4*)(pos + (size_t)l * 512 + d);
        float4 p1 = *(const float4*)(pos + (size_t)l * 512 + d + 4);
        float a[8] = {t0.x + p0.x, t0.y + p0.y, t0.z + p0.z, t0.w + p0.w,
                      t1.x + p1.x, t1.y + p1.y, t1.z + p1.z, t1.w + p1.w};
        unsigned int xp[4];
        #pragma unroll
        for (int i = 0; i < 4; ++i)
            xp[i] = (unsigned int)f2bf(a[2 * i]) | ((unsigned int)f2bf(a[2 * i + 1]) << 16);
        *(uint4*)(x + row * 512 + d) = *(uint4*)xp;
        float s = 0.f, s2 = 0.f;
        #pragma unroll
        for (int i = 0; i < 8; ++i) { s += a[i]; s2 += a[i] * a[i]; }
        #pragma unroll
        for (int o = 32; o > 0; o >>= 1) { s += __shfl_down(s, o); s2 += __shfl_down(s2, o); }
        s = __shfl(s, 0); s2 = __shfl(s2, 0);
        float m = s * (1.0f / 512.0f);
        float rinv = 1.0f / sqrtf(s2 * (1.0f / 512.0f) - m * m + 1e-5f);
        float4 ga = *(const float4*)(g0 + d), gb = *(const float4*)(g0 + d + 4);
        float4 ba = *(const float4*)(b0 + d), bb2 = *(const float4*)(b0 + d + 4);
        float gg[8] = {ga.x, ga.y, ga.z, ga.w, gb.x, gb.y, gb.z, gb.w};
        float bb[8] = {ba.x, ba.y, ba.z, ba.w, bb2.x, bb2.y, bb2.z, bb2.w};
        unsigned int hp[4];
        #pragma unroll
        for (int i = 0; i < 4; ++i) {
            unsigned short lo = f2bf((a[2 * i]     - m) * rinv * gg[2 * i]     + bb[2 * i]);
            unsigned short hi = f2bf((a[2 * i + 1] - m) * rinv * gg[2 * i + 1] + bb[2 * i + 1]);
            hp[i] = (unsigned int)lo | ((unsigned int)hi << 16);
        }
        *(uint4*)(hl + row * 512 + d) = *(uint4*)hp;
    } else if (blk < 6240) {
        int id = blk - 4096;
        int tx = t & 31, ty = t >> 5;
        const float* in; unsigned short* out; int R, C, bx, by, ldo;
        if (id < 1024) {
            int l = id >> 9, r = id & 511;
            in = w1 + l * 524288; out = w1T + l * 524288;
            R = 512; C = 1024; bx = r & 31; by = r >> 5; ldo = 512;
        } else if (id < 2048) {
            int l = (id - 1024) >> 9, r = (id - 1024) & 511;
            in = w2 + l * 524288; out = w2T + l * 524288;
            R = 1024; C = 512; bx = r & 15; by = r >> 4; ldo = 1024;
        } else {
            int g = (id - 2048) >> 5, r = (id - 2048) & 31;
            in = (g == 0) ? wa : (g == 1) ? wb : wc;
            out = wabcT + g * 32768;
            R = 512; C = 64; bx = r & 1; by = r >> 1; ldo = 512;
        }
        __shared__ unsigned short tile[32][33];
        int c0 = bx * 32, r0 = by * 32;
        for (int i = ty; i < 32; i += 8) {
            int r = r0 + i, c = c0 + tx;
            tile[i][tx] = (r < R && c < C) ? f2bf(in[(size_t)r * C + c]) : (unsigned short)0;
        }
        __syncthreads();
        for (int i = ty; i < 32; i += 8) {
            int c = c0 + i, r = r0 + tx;
            if (r < R && c < C) out[(size_t)c * ldo + r] = tile[tx][i];
        }
    } else {
        int g = blk - 6240;
        const float* src = (g == 0) ? ca : (g == 1) ? cb : cc;
        unsigned short* dst = clsb + g * 4096;
        for (int i = t; i < 4096; i += 256) dst[i] = f2bf(src[i]);
    }
}

// ------- LayerNorm, one wave per row, XCD-swizzled block->row mapping -------
__global__ __launch_bounds__(256) void ln_kernel(const unsigned short* __restrict__ x,
        const float* __restrict__ g, const float* __restrict__ b,
        unsigned short* __restrict__ out) {
    int wave = threadIdx.x >> 6, lane = threadIdx.x & 63;
    long row = swizzled_row(blockIdx.x, wave);
    int d = lane * 8;
    uint4 xp = *(const uint4*)(x + row * 512 + d);
    const unsigned int* xw = (const unsigned int*)&xp;
    float a[8];
    #pragma unroll
    for (int i = 0; i < 4; ++i) {
        a[2 * i]     = bf2f((unsigned short)(xw[i] & 0xffff));
        a[2 * i + 1] = bf2f((unsigned short)(xw[i] >> 16));
    }
    float s = 0.f, s2 = 0.f;
    #pragma unroll
    for (int i = 0; i < 8; ++i) { s += a[i]; s2 += a[i] * a[i]; }
    #pragma unroll
    for (int o = 32; o > 0; o >>= 1) { s += __shfl_down(s, o); s2 += __shfl_down(s2, o); }
    s = __shfl(s, 0); s2 = __shfl(s2, 0);
    float m = s * (1.0f / 512.0f);
    float rinv = 1.0f / sqrtf(s2 * (1.0f / 512.0f) - m * m + 1e-5f);
    float4 g0 = *(const float4*)(g + d), g1 = *(const float4*)(g + d + 4);
    float4 b0 = *(const float4*)(b + d), b1 = *(const float4*)(b + d + 4);
    float gg[8] = {g0.x, g0.y, g0.z, g0.w, g1.x, g1.y, g1.z, g1.w};
    float bb[8] = {b0.x, b0.y, b0.z, b0.w, b1.x, b1.y, b1.z, b1.w};
    unsigned int hp[4];
    #pragma unroll
    for (int i = 0; i < 4; ++i) {
        unsigned short lo = f2bf((a[2 * i]     - m) * rinv * gg[2 * i]     + bb[2 * i]);
        unsigned short hi = f2bf((a[2 * i + 1] - m) * rinv * gg[2 * i + 1] + bb[2 * i + 1]);
        hp[i] = (unsigned int)lo | ((unsigned int)hi << 16);
    }
    *(uint4*)(out + row * 512 + d) = *(uint4*)hp;
}

// ------- MFMA GEMM: m97 structure — global_load_lds(16B) staging, linear LDS,
//         2-barrier K-loop, swapped-operand packed epilogue -------
#define EPI_GELU_BF16  0
#define EPI_RES_BF16   1

template <int EPI, int TN>
__global__ __launch_bounds__(256) void gemm_gl(
        const unsigned short* __restrict__ A, int lda,
        const unsigned short* __restrict__ BT, int ldb,
        const float* __restrict__ bias,
        const unsigned short* __restrict__ xres,
        unsigned short* __restrict__ Cout, int ldc, int K) {
    constexpr int NJ = TN / 32;          // acc cols per wave
    constexpr int BCH = TN / 64;         // B staging chunks per wave (128->2, 64->1)
    // LINEAR layouts (no padding) — required by global_load_lds lane mapping
    __shared__ unsigned short As[128 * 32] __attribute__((aligned(16)));
    __shared__ unsigned short Bs[TN * 32] __attribute__((aligned(16)));
    const int t = threadIdx.x;
    const int lane = t & 63, wave = t >> 6;
    const int quad = lane >> 4, l16 = lane & 15;
    const int wm = (wave >> 1) * 64, wn = (wave & 1) * (TN / 2);
    const long tileM = (long)blockIdx.x * 128, tileN = (long)blockIdx.y * TN;

    // staging: chunk = 16 rows x 32 cols (1 KiB). lane l -> row +l/4, col (l&3)*8
    const int lr = lane >> 2, lc = (lane & 3) * 8;
    const unsigned short* gA0 = A + (tileM + wave * 32 + lr) * (size_t)lda + lc;
    const unsigned short* gA1 = gA0 + 16 * (size_t)lda;
    unsigned short* lA0 = &As[wave * 1024];   // 2 chunks * 512 shorts
    unsigned short* lA1 = lA0 + 512;
    const unsigned short* gB0 = BT + (tileN + wave * (BCH * 16) + lr) * (size_t)ldb + lc;
    const unsigned short* gB1 = gB0 + 16 * (size_t)ldb;
    unsigned short* lB0 = &Bs[wave * (BCH * 512)];
    unsigned short* lB1 = lB0 + 512;

    v4f acc[4][NJ] = {};

    // prologue: stage tile 0
    glds16(gA0, lA0); glds16(gA1, lA1);
    glds16(gB0, lB0);
    if (BCH == 2) glds16(gB1, lB1);
    gA0 += 32; gA1 += 32; gB0 += 32; gB1 += 32;

    const int nk = K >> 5;
    for (int kk = 0; kk < nk; ++kk) {
        asm volatile("s_waitcnt vmcnt(0)" ::: "memory");
        __syncthreads();                       // tile kk resident in LDS for all waves
        v8s af[4], bfr[NJ];
        #pragma unroll
        for (int i = 0; i < 4; ++i)
            af[i] = *(const v8s*)&As[(wm + i * 16 + l16) * 32 + quad * 8];
        #pragma unroll
        for (int j = 0; j < NJ; ++j)
            bfr[j] = *(const v8s*)&Bs[(wn + j * 16 + l16) * 32 + quad * 8];
        #pragma unroll
        for (int i = 0; i < 4; ++i)
            #pragma unroll
            for (int j = 0; j < NJ; ++j)
                acc[i][j] = __builtin_amdgcn_mfma_f32_16x16x32_bf16(bfr[j], af[i], acc[i][j], 0, 0, 0);
        __syncthreads();                       // all waves done reading LDS
        if (kk + 1 < nk) {
            glds16(gA0, lA0); glds16(gA1, lA1);
            glds16(gB0, lB0);
            if (BCH == 2) glds16(gB1, lB1);
            gA0 += 32; gA1 += 32; gB0 += 32; gB1 += 32;
        }
    }

    // packed epilogue: fixed m per lane, 4 consecutive n per acc
    #pragma unroll
    for (int i = 0; i < 4; ++i) {
        long m = tileM + wm + i * 16 + l16;
        #pragma unroll
        for (int j = 0; j < NJ; ++j) {
            long n0 = tileN + wn + j * 16 + quad * 4;
            float4 bi = *(const float4*)&bias[n0];
            const float* bip = (const float*)&bi;
            unsigned short pk[4];
            if (EPI == EPI_GELU_BF16) {
                #pragma unroll
                for (int r = 0; r < 4; ++r)
                    pk[r] = f2bf(fast_gelu(acc[i][j][r] + bip[r]));
            } else {
                ushort4 xr4 = *(const ushort4*)&xres[m * ldc + n0];
                const unsigned short* xp = (const unsigned short*)&xr4;
                #pragma unroll
                for (int r = 0; r < 4; ++r)
                    pk[r] = f2bf(acc[i][j][r] + bip[r] + bf2f(xp[r]));
            }
            *(ushort4*)&Cout[m * ldc + n0] = *(ushort4*)pk;
        }
    }
}

// ------- fused tanh-GEMM + class-GEMM, global_load_lds staging, TM=128 -------
__global__ __launch_bounds__(256) void tanh_class_kernel(
        const unsigned short* __restrict__ A,
        const unsigned short* __restrict__ WT,
        const unsigned short* __restrict__ cls,
        unsigned short* __restrict__ uu) {
    __shared__ unsigned short As[128 * 32] __attribute__((aligned(16)));
    __shared__ unsigned short Bs[64 * 32] __attribute__((aligned(16)));
    __shared__ unsigned short P[128 * 72] __attribute__((aligned(16)));
    const int t = threadIdx.x;
    const int lane = t & 63, wave = t >> 6;
    const int quad = lane >> 4, l16 = lane & 15;
    const int wm = (wave >> 1) * 64, wn = (wave & 1) * 32;
    const long tileM = (long)blockIdx.x * 128;
    const int g = blockIdx.y;

    const unsigned short* BT = WT + g * 32768;
    v8s cf[2][2];
    #pragma unroll
    for (int ks = 0; ks < 2; ++ks)
        #pragma unroll
        for (int j = 0; j < 2; ++j)
            cf[ks][j] = *(const v8s*)&cls[g * 4096 + (wn + j * 16 + l16) * 64 + ks * 32 + quad * 8];

    const int lr = lane >> 2, lc = (lane & 3) * 8;
    const unsigned short* gA0 = A + (tileM + wave * 32 + lr) * 512 + lc;
    const unsigned short* gA1 = gA0 + 16 * 512;
    unsigned short* lA0 = &As[wave * 1024];
    unsigned short* lA1 = lA0 + 512;
    const unsigned short* gB0 = BT + (wave * 16 + lr) * 512 + lc;
    unsigned short* lB0 = &Bs[wave * 512];

    v4f acc[4][2] = {};

    glds16(gA0, lA0); glds16(gA1, lA1); glds16(gB0, lB0);
    gA0 += 32; gA1 += 32; gB0 += 32;

    for (int kk = 0; kk < 16; ++kk) {
        asm volatile("s_waitcnt vmcnt(0)" ::: "memory");
        __syncthreads();
        v8s af[4], bfr[2];
        #pragma unroll
        for (int i = 0; i < 4; ++i)
            af[i] = *(const v8s*)&As[(wm + i * 16 + l16) * 32 + quad * 8];
        #pragma unroll
        for (int j = 0; j < 2; ++j)
            bfr[j] = *(const v8s*)&Bs[(wn + j * 16 + l16) * 32 + quad * 8];
        #pragma unroll
        for (int i = 0; i < 4; ++i)
            #pragma unroll
            for (int j = 0; j < 2; ++j)
                acc[i][j] = __builtin_amdgcn_mfma_f32_16x16x32_bf16(bfr[j], af[i], acc[i][j], 0, 0, 0);
        __syncthreads();
        if (kk + 1 < 16) {
            glds16(gA0, lA0); glds16(gA1, lA1); glds16(gB0, lB0);
            gA0 += 32; gA1 += 32; gB0 += 32;
        }
    }

    #pragma unroll
    for (int i = 0; i < 4; ++i) {
        int m = wm + i * 16 + l16;
        #pragma unroll
        for (int j = 0; j < 2; ++j) {
            int n0 = wn + j * 16 + quad * 4;
            unsigned short pk[4];
            #pragma unroll
            for (int r = 0; r < 4; ++r) pk[r] = f2bf(fast_tanh(acc[i][j][r]));
            *(ushort4*)&P[m * 72 + n0] = *(ushort4*)pk;
        }
    }
    __syncthreads();

    v4f acc2[4][2] = {};
    #pragma unroll
    for (int ks = 0; ks < 2; ++ks) {
        v8s paf[4];
        #pragma unroll
        for (int i = 0; i < 4; ++i)
            paf[i] = *(const v8s*)&P[(wm + i * 16 + l16) * 72 + ks * 32 + quad * 8];
        #pragma unroll
        for (int i = 0; i < 4; ++i)
            #pragma unroll
            for (int j = 0; j < 2; ++j)
                acc2[i][j] = __builtin_amdgcn_mfma_f32_16x16x32_bf16(cf[ks][j], paf[i], acc2[i][j], 0, 0, 0);
    }

    #pragma unroll
    for (int i = 0; i < 4; ++i) {
        long m = tileM + wm + i * 16 + l16;
        #pragma unroll
        for (int j = 0; j < 2; ++j) {
            int c0 = wn + j * 16 + quad * 4;
            unsigned short pk[4];
            #pragma unroll
            for (int r = 0; r < 4; ++r) pk[r] = f2bf(acc2[i][j][r]);
            *(ushort4*)&uu[m * 192 + g * 64 + c0] = *(ushort4*)pk;
        }
    }
}

// ------- exact ordered-triplet scan pass 1 -------
__global__ __launch_bounds__(64) void scan_part_kernel(const unsigned short* __restrict__ u,
                                                       float* __restrict__ part) {
    int b = blockIdx.x, seg = blockIdx.y;
    int c = threadIdx.x;
    int l0 = seg * 32;
    int l1 = l0 + 32; if (l1 > 2047) l1 = 2047;
    float sA = 0.f, sB = 0.f, sC = 0.f, T = 0.f, M = 0.f, U = 0.f;
    const unsigned short* base = u + ((size_t)b * LSEQ + l0) * 192 + c;
    for (int l = l0; l < l1; ++l) {
        float ua = bf2f(base[0]), ub = bf2f(base[64]), uc = bf2f(base[128]);
        base += 192;
        U += uc * T;
        M += uc * sB;
        T += ub * sA;
        sA += ua; sB += ub; sC += uc;
    }
    float* p = part + ((size_t)(b * 64 + seg)) * 384 + c;
    p[0] = sA; p[64] = sB; p[128] = sC; p[192] = T; p[256] = M; p[320] = U;
}

// ------- merged: segment combine + final LN + Wq GEMV -------
__global__ __launch_bounds__(64) void combine_final_kernel(const float* __restrict__ part,
        const unsigned short* __restrict__ x,
        const float* __restrict__ qw, const float* __restrict__ qb,
        const float* __restrict__ Wq, const float* __restrict__ bq,
        float* __restrict__ out, float inv_denom) {
    int b = blockIdx.x;
    int c = threadIdx.x;
    const float* p = part + (size_t)b * 64 * 384 + c;
    float A = p[0], B = p[64], Tt = p[192], Mt = p[256], Ut = p[320];
    for (int seg = 1; seg < 64; ++seg) {
        const float* q2 = p + seg * 384;
        float a2 = q2[0], b2 = q2[64], c2 = q2[128], t2 = q2[192], m2 = q2[256], u2 = q2[320];
        float Un = Ut + u2 + c2 * Tt + A * m2;
        float Tn = Tt + t2 + A * b2;
        float Mn = Mt + m2 + B * c2;
        A += a2; B += b2;
        Ut = Un; Tt = Tn; Mt = Mn;
    }
    __shared__ float q[512];
    __shared__ float mv[2];
    const unsigned short* xr = x + ((size_t)b * LSEQ + (LSEQ - 1)) * 512;
    float s1 = 0.f, s2 = 0.f;
    for (int i = c; i < 512; i += 64) { float v = bf2f(xr[i]); q[i] = v; s1 += v; s2 += v * v; }
    #pragma unroll
    for (int o = 32; o > 0; o >>= 1) { s1 += __shfl_down(s1, o); s2 += __shfl_down(s2, o); }
    if (c == 0) {
        float m = s1 * (1.0f / 512.0f);
        float var = s2 * (1.0f / 512.0f) - m * m;
        mv[0] = m; mv[1] = 1.0f / sqrtf(var + 1e-5f);
    }
    __syncthreads();
    float m = mv[0], r = mv[1];
    for (int i = c; i < 512; i += 64) q[i] = (q[i] - m) * r * qw[i] + qb[i];
    __syncthreads();
    float acc = 0.f;
    for (int d = 0; d < 512; ++d) acc += q[d] * Wq[d * 64 + c];
    out[b * 64 + c] = Ut * inv_denom + acc + bq[c];
}

extern "C" void kernel_launch(void* const* d_in, const int* in_sizes, int n_in,
                              void* d_out, int out_size, void* d_ws, size_t ws_size,
                              hipStream_t stream) {
    const int*   token_ids   = (const int*)d_in[0];
    const float* tok_emb     = (const float*)d_in[1];
    const float* pos_emb     = (const float*)d_in[2];
    const float* stem_ln_w   = (const float*)d_in[3];
    const float* stem_ln_b   = (const float*)d_in[4];
    const float* stem_w1     = (const float*)d_in[5];
    const float* stem_b1     = (const float*)d_in[6];
    const float* stem_w2     = (const float*)d_in[7];
    const float* stem_b2     = (const float*)d_in[8];
    const float* role_ln_w   = (const float*)d_in[9];
    const float* role_ln_b   = (const float*)d_in[10];
    const float* Wa          = (const float*)d_in[11];
    const float* Wb          = (const float*)d_in[12];
    const float* Wc          = (const float*)d_in[13];
    const float* class_a     = (const float*)d_in[14];
    const float* class_b     = (const float*)d_in[15];
    const float* class_c     = (const float*)d_in[16];
    const float* query_ln_w  = (const float*)d_in[17];
    const float* query_ln_b  = (const float*)d_in[18];
    const float* Wq          = (const float*)d_in[19];
    const float* bq          = (const float*)d_in[20];
    float* out = (float*)d_out;

    char* wsb = (char*)d_ws;
    unsigned short* x    = (unsigned short*)(wsb);              // 16,777,216
    unsigned short* hl   = (unsigned short*)(wsb + 16777216);   // 16,777,216
    unsigned short* Hb   = (unsigned short*)(wsb + 33554432);   // 33,554,432
    unsigned short* uu   = (unsigned short*)(wsb + 67108864);   // 6,291,456
    float* part          = (float*)(wsb + 73400320);            // 786,432
    unsigned short* w1T  = (unsigned short*)(wsb + 74188800);   // 2,097,152
    unsigned short* w2T  = (unsigned short*)(wsb + 76285952);   // 2,097,152
    unsigned short* wabcT= (unsigned short*)(wsb + 78383104);   // 196,608
    unsigned short* clsb = (unsigned short*)(wsb + 78579712);   // 24,576

    setup_kernel<<<6243, 256, 0, stream>>>(token_ids, tok_emb, pos_emb,
        stem_ln_w, stem_ln_b, x, hl,
        stem_w1, stem_w2, Wa, Wb, Wc, class_a, class_b, class_c,
        w1T, w2T, wabcT, clsb);

    for (int i = 0; i < 2; ++i) {
        if (i > 0)
            ln_kernel<<<NROWS / 4, 256, 0, stream>>>(x, stem_ln_w + 512, stem_ln_b + 512, hl);
        gemm_gl<EPI_GELU_BF16, 128><<<dim3(128, 8), 256, 0, stream>>>(
            hl, 512, w1T + i * 524288, 512, stem_b1 + i * 1024, nullptr, Hb, 1024, 512);
        gemm_gl<EPI_RES_BF16, 64><<<dim3(128, 8), 256, 0, stream>>>(
            Hb, 1024, w2T + i * 524288, 1024, stem_b2 + i * 512, x, x, 512, 1024);
    }

    ln_kernel<<<NROWS / 4, 256, 0, stream>>>(x, role_ln_w, role_ln_b, hl);

    tanh_class_kernel<<<dim3(128, 3), 256, 0, stream>>>(hl, wabcT, clsb, uu);

    scan_part_kernel<<<dim3(NB, 64), 64, 0, stream>>>(uu, part);

    float inv_denom = (float)(6.0 / (2047.0 * 2046.0 * 2045.0));
    combine_final_kernel<<<NB, 64, 0, stream>>>(part, x, query_ln_w, query_ln_b,
                                                Wq, bq, out, inv_denom);
}

// Round 2
// 342.842 us; speedup vs baseline: 1.0375x; 1.0375x over previous
//
#include <hip/hip_runtime.h>

#define NROWS 16384   // B*L
#define LSEQ  2048
#define NB    8

typedef short v8s __attribute__((ext_vector_type(8)));
typedef float v4f __attribute__((ext_vector_type(4)));

__device__ __forceinline__ unsigned short f2bf(float f) {
    unsigned int u = __float_as_uint(f);
    return (unsigned short)((u + 0x7fffu + ((u >> 16) & 1u)) >> 16);
}
__device__ __forceinline__ float bf2f(unsigned short u) {
    return __uint_as_float(((unsigned int)u) << 16);
}

// async global->LDS, 16B per lane; LDS dest is wave-uniform base + lane*16
__device__ __forceinline__ void glds16(const void* g, void* l) {
    __builtin_amdgcn_global_load_lds(
        (__attribute__((address_space(1))) void*)g,
        (__attribute__((address_space(3))) void*)l,
        16, 0, 0);
}

// fast exact-GELU: Abramowitz-Stegun 5-term erf, |err|<1.5e-7
__device__ __forceinline__ float fast_gelu(float v) {
    float z = fabsf(v) * 0.70710678118654752f;
    float t = __builtin_amdgcn_rcpf(1.0f + 0.3275911f * z);
    float poly = t * (0.254829592f + t * (-0.284496736f + t * (1.421413741f +
                 t * (-1.453152027f + t * 1.061405429f))));
    float erfz = 1.0f - poly * __expf(-z * z);
    float er = copysignf(erfz, v);
    return 0.5f * v * (1.0f + er);
}
__device__ __forceinline__ float fast_tanh(float y) {
    float e = __expf(2.0f * y);
    return (e - 1.0f) * __builtin_amdgcn_rcpf(e + 1.0f);
}

// XCD row-swizzle: block b (of 4096, 4 rows each) -> rows of 128-row tile T with
// T%8 == b%8, so the producer's XCD matches the GEMM reader's XCD (= (m>>7)%8).
__device__ __forceinline__ long swizzled_row(int b, int wave) {
    int T = (b & 7) + (((b >> 3) & 15) << 3);   // 0..127, T%8 == b%8
    int chunk = b >> 7;                          // 0..31
    return (long)T * 128 + chunk * 4 + wave;
}

// ------- merged setup: embed (blocks 0..4095, XCD-swizzled) | weight transposes
//         (4096..6239) | class converts (6240..6242); embed also emits LN0(hl) -------
__global__ __launch_bounds__(256) void setup_kernel(
        const int* __restrict__ ids,
        const float* __restrict__ tok, const float* __restrict__ pos,
        const float* __restrict__ g0, const float* __restrict__ b0,
        unsigned short* __restrict__ x, unsigned short* __restrict__ hl,
        const float* __restrict__ w1, const float* __restrict__ w2,
        const float* __restrict__ wa, const float* __restrict__ wb, const float* __restrict__ wc,
        const float* __restrict__ ca, const float* __restrict__ cb, const float* __restrict__ cc,
        unsigned short* __restrict__ w1T, unsigned short* __restrict__ w2T,
        unsigned short* __restrict__ wabcT, unsigned short* __restrict__ clsb) {
    int blk = blockIdx.x;
    int t = threadIdx.x;
    if (blk < 4096) {
        int wave = t >> 6, lane = t & 63;
        long row = swizzled_row(blk, wave);
        int l = (int)(row & (LSEQ - 1));
        int id = ids[row];
        int d = lane * 8;
        float4 t0 = *(const float4*)(tok + (size_t)id * 512 + d);
        float4 t1 = *(const float4*)(tok + (size_t)id * 512 + d + 4);
        float4 p0 = *(const float4*)(pos + (size_t)l * 512 + d);
        float4 p1 = *(const float4*)(pos + (size_t)l * 512 + d + 4);
        float a[8] = {t0.x + p0.x, t0.y + p0.y, t0.z + p0.z, t0.w + p0.w,
                      t1.x + p1.x, t1.y + p1.y, t1.z + p1.z, t1.w + p1.w};
        unsigned int xp[4];
        #pragma unroll
        for (int i = 0; i < 4; ++i)
            xp[i] = (unsigned int)f2bf(a[2 * i]) | ((unsigned int)f2bf(a[2 * i + 1]) << 16);
        *(uint4*)(x + row * 512 + d) = *(uint4*)xp;
        float s = 0.f, s2 = 0.f;
        #pragma unroll
        for (int i = 0; i < 8; ++i) { s += a[i]; s2 += a[i] * a[i]; }
        #pragma unroll
        for (int o = 32; o > 0; o >>= 1) { s += __shfl_down(s, o); s2 += __shfl_down(s2, o); }
        s = __shfl(s, 0); s2 = __shfl(s2, 0);
        float m = s * (1.0f / 512.0f);
        float rinv = 1.0f / sqrtf(s2 * (1.0f / 512.0f) - m * m + 1e-5f);
        float4 ga = *(const float4*)(g0 + d), gb = *(const float4*)(g0 + d + 4);
        float4 ba = *(const float4*)(b0 + d), bb2 = *(const float4*)(b0 + d + 4);
        float gg[8] = {ga.x, ga.y, ga.z, ga.w, gb.x, gb.y, gb.z, gb.w};
        float bb[8] = {ba.x, ba.y, ba.z, ba.w, bb2.x, bb2.y, bb2.z, bb2.w};
        unsigned int hp[4];
        #pragma unroll
        for (int i = 0; i < 4; ++i) {
            unsigned short lo = f2bf((a[2 * i]     - m) * rinv * gg[2 * i]     + bb[2 * i]);
            unsigned short hi = f2bf((a[2 * i + 1] - m) * rinv * gg[2 * i + 1] + bb[2 * i + 1]);
            hp[i] = (unsigned int)lo | ((unsigned int)hi << 16);
        }
        *(uint4*)(hl + row * 512 + d) = *(uint4*)hp;
    } else if (blk < 6240) {
        int id = blk - 4096;
        int tx = t & 31, ty = t >> 5;
        const float* in; unsigned short* out; int R, C, bx, by, ldo;
        if (id < 1024) {
            int l = id >> 9, r = id & 511;
            in = w1 + l * 524288; out = w1T + l * 524288;
            R = 512; C = 1024; bx = r & 31; by = r >> 5; ldo = 512;
        } else if (id < 2048) {
            int l = (id - 1024) >> 9, r = (id - 1024) & 511;
            in = w2 + l * 524288; out = w2T + l * 524288;
            R = 1024; C = 512; bx = r & 15; by = r >> 4; ldo = 1024;
        } else {
            int g = (id - 2048) >> 5, r = (id - 2048) & 31;
            in = (g == 0) ? wa : (g == 1) ? wb : wc;
            out = wabcT + g * 32768;
            R = 512; C = 64; bx = r & 1; by = r >> 1; ldo = 512;
        }
        __shared__ unsigned short tile[32][33];
        int c0 = bx * 32, r0 = by * 32;
        for (int i = ty; i < 32; i += 8) {
            int r = r0 + i, c = c0 + tx;
            tile[i][tx] = (r < R && c < C) ? f2bf(in[(size_t)r * C + c]) : (unsigned short)0;
        }
        __syncthreads();
        for (int i = ty; i < 32; i += 8) {
            int c = c0 + i, r = r0 + tx;
            if (r < R && c < C) out[(size_t)c * ldo + r] = tile[tx][i];
        }
    } else {
        int g = blk - 6240;
        const float* src = (g == 0) ? ca : (g == 1) ? cb : cc;
        unsigned short* dst = clsb + g * 4096;
        for (int i = t; i < 4096; i += 256) dst[i] = f2bf(src[i]);
    }
}

// ------- LayerNorm, one wave per row, XCD-swizzled block->row mapping -------
__global__ __launch_bounds__(256) void ln_kernel(const unsigned short* __restrict__ x,
        const float* __restrict__ g, const float* __restrict__ b,
        unsigned short* __restrict__ out) {
    int wave = threadIdx.x >> 6, lane = threadIdx.x & 63;
    long row = swizzled_row(blockIdx.x, wave);
    int d = lane * 8;
    uint4 xp = *(const uint4*)(x + row * 512 + d);
    const unsigned int* xw = (const unsigned int*)&xp;
    float a[8];
    #pragma unroll
    for (int i = 0; i < 4; ++i) {
        a[2 * i]     = bf2f((unsigned short)(xw[i] & 0xffff));
        a[2 * i + 1] = bf2f((unsigned short)(xw[i] >> 16));
    }
    float s = 0.f, s2 = 0.f;
    #pragma unroll
    for (int i = 0; i < 8; ++i) { s += a[i]; s2 += a[i] * a[i]; }
    #pragma unroll
    for (int o = 32; o > 0; o >>= 1) { s += __shfl_down(s, o); s2 += __shfl_down(s2, o); }
    s = __shfl(s, 0); s2 = __shfl(s2, 0);
    float m = s * (1.0f / 512.0f);
    float rinv = 1.0f / sqrtf(s2 * (1.0f / 512.0f) - m * m + 1e-5f);
    float4 g0 = *(const float4*)(g + d), g1 = *(const float4*)(g + d + 4);
    float4 b0 = *(const float4*)(b + d), b1 = *(const float4*)(b + d + 4);
    float gg[8] = {g0.x, g0.y, g0.z, g0.w, g1.x, g1.y, g1.z, g1.w};
    float bb[8] = {b0.x, b0.y, b0.z, b0.w, b1.x, b1.y, b1.z, b1.w};
    unsigned int hp[4];
    #pragma unroll
    for (int i = 0; i < 4; ++i) {
        unsigned short lo = f2bf((a[2 * i]     - m) * rinv * gg[2 * i]     + bb[2 * i]);
        unsigned short hi = f2bf((a[2 * i + 1] - m) * rinv * gg[2 * i + 1] + bb[2 * i + 1]);
        hp[i] = (unsigned int)lo | ((unsigned int)hi << 16);
    }
    *(uint4*)(out + row * 512 + d) = *(uint4*)hp;
}

// ------- MFMA GEMM: double-buffered global_load_lds, counted vmcnt, raw barriers
//         (T3 minimum-2-phase recipe: stage(next) FIRST, counted wait, no vmcnt(0)
//          drain in steady state) -------
#define EPI_GELU_BF16  0
#define EPI_RES_BF16   1

template <int EPI, int TN>
__global__ __launch_bounds__(256) void gemm_db(
        const unsigned short* __restrict__ A, int lda,
        const unsigned short* __restrict__ BT, int ldb,
        const float* __restrict__ bias,
        const unsigned short* __restrict__ xres,
        unsigned short* __restrict__ Cout, int ldc, int K) {
    constexpr int NJ = TN / 32;          // acc cols per wave
    constexpr int BCH = TN / 64;         // B staging chunks per wave (128->2, 64->1)
    constexpr int NLOADS = 2 + BCH;      // glds16 per wave per K-tile
    // LINEAR layouts (no padding) — required by global_load_lds lane mapping
    __shared__ unsigned short As[2][128 * 32] __attribute__((aligned(16)));
    __shared__ unsigned short Bs[2][TN * 32] __attribute__((aligned(16)));
    const int t = threadIdx.x;
    const int lane = t & 63, wave = t >> 6;
    const int quad = lane >> 4, l16 = lane & 15;
    const int wm = (wave >> 1) * 64, wn = (wave & 1) * (TN / 2);
    const long tileM = (long)blockIdx.x * 128, tileN = (long)blockIdx.y * TN;

    // staging: chunk = 16 rows x 32 cols (1 KiB). lane l -> row +l/4, col (l&3)*8
    const int lr = lane >> 2, lc = (lane & 3) * 8;
    const unsigned short* gA0 = A + (tileM + wave * 32 + lr) * (size_t)lda + lc;
    const unsigned short* gA1 = gA0 + 16 * (size_t)lda;
    const unsigned short* gB0 = BT + (tileN + wave * (BCH * 16) + lr) * (size_t)ldb + lc;
    const unsigned short* gB1 = gB0 + 16 * (size_t)ldb;

    v4f acc[4][NJ] = {};

    auto stage = [&](int buf) {
        glds16(gA0, &As[buf][wave * 1024]);
        glds16(gA1, &As[buf][wave * 1024 + 512]);
        glds16(gB0, &Bs[buf][wave * (BCH * 512)]);
        if constexpr (BCH == 2) glds16(gB1, &Bs[buf][wave * 1024 + 512]);
        gA0 += 32; gA1 += 32; gB0 += 32;
        if constexpr (BCH == 2) gB1 += 32;
    };

    stage(0);                             // tile 0 in flight into buf 0

    const int nk = K >> 5;
    int cur = 0;
    for (int kk = 0; kk < nk; ++kk) {
        if (kk + 1 < nk) {
            stage(cur ^ 1);               // issue next tile BEFORE waiting
            // wait only for current tile's loads (oldest); next's stay in flight
            asm volatile("s_waitcnt vmcnt(%0)" :: "i"(NLOADS) : "memory");
        } else {
            asm volatile("s_waitcnt vmcnt(0)" ::: "memory");
        }
        asm volatile("s_barrier" ::: "memory");   // raw: no compiler vmcnt(0) drain
        v8s af[4], bfr[NJ];
        #pragma unroll
        for (int i = 0; i < 4; ++i)
            af[i] = *(const v8s*)&As[cur][(wm + i * 16 + l16) * 32 + quad * 8];
        #pragma unroll
        for (int j = 0; j < NJ; ++j)
            bfr[j] = *(const v8s*)&Bs[cur][(wn + j * 16 + l16) * 32 + quad * 8];
        #pragma unroll
        for (int i = 0; i < 4; ++i)
            #pragma unroll
            for (int j = 0; j < NJ; ++j)
                acc[i][j] = __builtin_amdgcn_mfma_f32_16x16x32_bf16(bfr[j], af[i], acc[i][j], 0, 0, 0);
        if (kk + 1 < nk)
            asm volatile("s_barrier" ::: "memory");  // all reads of buf[cur] done before restage
        cur ^= 1;
    }

    // packed epilogue: fixed m per lane, 4 consecutive n per acc
    #pragma unroll
    for (int i = 0; i < 4; ++i) {
        long m = tileM + wm + i * 16 + l16;
        #pragma unroll
        for (int j = 0; j < NJ; ++j) {
            long n0 = tileN + wn + j * 16 + quad * 4;
            float4 bi = *(const float4*)&bias[n0];
            const float* bip = (const float*)&bi;
            unsigned short pk[4];
            if (EPI == EPI_GELU_BF16) {
                #pragma unroll
                for (int r = 0; r < 4; ++r)
                    pk[r] = f2bf(fast_gelu(acc[i][j][r] + bip[r]));
            } else {
                ushort4 xr4 = *(const ushort4*)&xres[m * ldc + n0];
                const unsigned short* xp = (const unsigned short*)&xr4;
                #pragma unroll
                for (int r = 0; r < 4; ++r)
                    pk[r] = f2bf(acc[i][j][r] + bip[r] + bf2f(xp[r]));
            }
            *(ushort4*)&Cout[m * ldc + n0] = *(ushort4*)pk;
        }
    }
}

// ------- fused tanh-GEMM + class-GEMM, double-buffered glds staging, TM=128 -------
__global__ __launch_bounds__(256) void tanh_class_kernel(
        const unsigned short* __restrict__ A,
        const unsigned short* __restrict__ WT,
        const unsigned short* __restrict__ cls,
        unsigned short* __restrict__ uu) {
    __shared__ unsigned short As[2][128 * 32] __attribute__((aligned(16)));
    __shared__ unsigned short Bs[2][64 * 32] __attribute__((aligned(16)));
    __shared__ unsigned short P[128 * 72] __attribute__((aligned(16)));
    const int t = threadIdx.x;
    const int lane = t & 63, wave = t >> 6;
    const int quad = lane >> 4, l16 = lane & 15;
    const int wm = (wave >> 1) * 64, wn = (wave & 1) * 32;
    const long tileM = (long)blockIdx.x * 128;
    const int g = blockIdx.y;

    const unsigned short* BT = WT + g * 32768;
    v8s cf[2][2];
    #pragma unroll
    for (int ks = 0; ks < 2; ++ks)
        #pragma unroll
        for (int j = 0; j < 2; ++j)
            cf[ks][j] = *(const v8s*)&cls[g * 4096 + (wn + j * 16 + l16) * 64 + ks * 32 + quad * 8];

    const int lr = lane >> 2, lc = (lane & 3) * 8;
    const unsigned short* gA0 = A + (tileM + wave * 32 + lr) * 512 + lc;
    const unsigned short* gA1 = gA0 + 16 * 512;
    const unsigned short* gB0 = BT + (wave * 16 + lr) * 512 + lc;

    v4f acc[4][2] = {};

    auto stage = [&](int buf) {
        glds16(gA0, &As[buf][wave * 1024]);
        glds16(gA1, &As[buf][wave * 1024 + 512]);
        glds16(gB0, &Bs[buf][wave * 512]);
        gA0 += 32; gA1 += 32; gB0 += 32;
    };

    stage(0);
    int cur = 0;
    for (int kk = 0; kk < 16; ++kk) {
        if (kk + 1 < 16) {
            stage(cur ^ 1);
            asm volatile("s_waitcnt vmcnt(3)" ::: "memory");
        } else {
            asm volatile("s_waitcnt vmcnt(0)" ::: "memory");
        }
        asm volatile("s_barrier" ::: "memory");
        v8s af[4], bfr[2];
        #pragma unroll
        for (int i = 0; i < 4; ++i)
            af[i] = *(const v8s*)&As[cur][(wm + i * 16 + l16) * 32 + quad * 8];
        #pragma unroll
        for (int j = 0; j < 2; ++j)
            bfr[j] = *(const v8s*)&Bs[cur][(wn + j * 16 + l16) * 32 + quad * 8];
        #pragma unroll
        for (int i = 0; i < 4; ++i)
            #pragma unroll
            for (int j = 0; j < 2; ++j)
                acc[i][j] = __builtin_amdgcn_mfma_f32_16x16x32_bf16(bfr[j], af[i], acc[i][j], 0, 0, 0);
        if (kk + 1 < 16)
            asm volatile("s_barrier" ::: "memory");
        cur ^= 1;
    }

    #pragma unroll
    for (int i = 0; i < 4; ++i) {
        int m = wm + i * 16 + l16;
        #pragma unroll
        for (int j = 0; j < 2; ++j) {
            int n0 = wn + j * 16 + quad * 4;
            unsigned short pk[4];
            #pragma unroll
            for (int r = 0; r < 4; ++r) pk[r] = f2bf(fast_tanh(acc[i][j][r]));
            *(ushort4*)&P[m * 72 + n0] = *(ushort4*)pk;
        }
    }
    __syncthreads();

    v4f acc2[4][2] = {};
    #pragma unroll
    for (int ks = 0; ks < 2; ++ks) {
        v8s paf[4];
        #pragma unroll
        for (int i = 0; i < 4; ++i)
            paf[i] = *(const v8s*)&P[(wm + i * 16 + l16) * 72 + ks * 32 + quad * 8];
        #pragma unroll
        for (int i = 0; i < 4; ++i)
            #pragma unroll
            for (int j = 0; j < 2; ++j)
                acc2[i][j] = __builtin_amdgcn_mfma_f32_16x16x32_bf16(cf[ks][j], paf[i], acc2[i][j], 0, 0, 0);
    }

    #pragma unroll
    for (int i = 0; i < 4; ++i) {
        long m = tileM + wm + i * 16 + l16;
        #pragma unroll
        for (int j = 0; j < 2; ++j) {
            int c0 = wn + j * 16 + quad * 4;
            unsigned short pk[4];
            #pragma unroll
            for (int r = 0; r < 4; ++r) pk[r] = f2bf(acc2[i][j][r]);
            *(ushort4*)&uu[m * 192 + g * 64 + c0] = *(ushort4*)pk;
        }
    }
}

// ------- exact ordered-triplet scan pass 1 -------
__global__ __launch_bounds__(64) void scan_part_kernel(const unsigned short* __restrict__ u,
                                                       float* __restrict__ part) {
    int b = blockIdx.x, seg = blockIdx.y;
    int c = threadIdx.x;
    int l0 = seg * 32;
    int l1 = l0 + 32; if (l1 > 2047) l1 = 2047;
    float sA = 0.f, sB = 0.f, sC = 0.f, T = 0.f, M = 0.f, U = 0.f;
    const unsigned short* base = u + ((size_t)b * LSEQ + l0) * 192 + c;
    for (int l = l0; l < l1; ++l) {
        float ua = bf2f(base[0]), ub = bf2f(base[64]), uc = bf2f(base[128]);
        base += 192;
        U += uc * T;
        M += uc * sB;
        T += ub * sA;
        sA += ua; sB += ub; sC += uc;
    }
    float* p = part + ((size_t)(b * 64 + seg)) * 384 + c;
    p[0] = sA; p[64] = sB; p[128] = sC; p[192] = T; p[256] = M; p[320] = U;
}

// ------- merged: segment combine + final LN + Wq GEMV -------
__global__ __launch_bounds__(64) void combine_final_kernel(const float* __restrict__ part,
        const unsigned short* __restrict__ x,
        const float* __restrict__ qw, const float* __restrict__ qb,
        const float* __restrict__ Wq, const float* __restrict__ bq,
        float* __restrict__ out, float inv_denom) {
    int b = blockIdx.x;
    int c = threadIdx.x;
    const float* p = part + (size_t)b * 64 * 384 + c;
    float A = p[0], B = p[64], Tt = p[192], Mt = p[256], Ut = p[320];
    for (int seg = 1; seg < 64; ++seg) {
        const float* q2 = p + seg * 384;
        float a2 = q2[0], b2 = q2[64], c2 = q2[128], t2 = q2[192], m2 = q2[256], u2 = q2[320];
        float Un = Ut + u2 + c2 * Tt + A * m2;
        float Tn = Tt + t2 + A * b2;
        float Mn = Mt + m2 + B * c2;
        A += a2; B += b2;
        Ut = Un; Tt = Tn; Mt = Mn;
    }
    __shared__ float q[512];
    __shared__ float mv[2];
    const unsigned short* xr = x + ((size_t)b * LSEQ + (LSEQ - 1)) * 512;
    float s1 = 0.f, s2 = 0.f;
    for (int i = c; i < 512; i += 64) { float v = bf2f(xr[i]); q[i] = v; s1 += v; s2 += v * v; }
    #pragma unroll
    for (int o = 32; o > 0; o >>= 1) { s1 += __shfl_down(s1, o); s2 += __shfl_down(s2, o); }
    if (c == 0) {
        float m = s1 * (1.0f / 512.0f);
        float var = s2 * (1.0f / 512.0f) - m * m;
        mv[0] = m; mv[1] = 1.0f / sqrtf(var + 1e-5f);
    }
    __syncthreads();
    float m = mv[0], r = mv[1];
    for (int i = c; i < 512; i += 64) q[i] = (q[i] - m) * r * qw[i] + qb[i];
    __syncthreads();
    float acc = 0.f;
    for (int d = 0; d < 512; ++d) acc += q[d] * Wq[d * 64 + c];
    out[b * 64 + c] = Ut * inv_denom + acc + bq[c];
}

extern "C" void kernel_launch(void* const* d_in, const int* in_sizes, int n_in,
                              void* d_out, int out_size, void* d_ws, size_t ws_size,
                              hipStream_t stream) {
    const int*   token_ids   = (const int*)d_in[0];
    const float* tok_emb     = (const float*)d_in[1];
    const float* pos_emb     = (const float*)d_in[2];
    const float* stem_ln_w   = (const float*)d_in[3];
    const float* stem_ln_b   = (const float*)d_in[4];
    const float* stem_w1     = (const float*)d_in[5];
    const float* stem_b1     = (const float*)d_in[6];
    const float* stem_w2     = (const float*)d_in[7];
    const float* stem_b2     = (const float*)d_in[8];
    const float* role_ln_w   = (const float*)d_in[9];
    const float* role_ln_b   = (const float*)d_in[10];
    const float* Wa          = (const float*)d_in[11];
    const float* Wb          = (const float*)d_in[12];
    const float* Wc          = (const float*)d_in[13];
    const float* class_a     = (const float*)d_in[14];
    const float* class_b     = (const float*)d_in[15];
    const float* class_c     = (const float*)d_in[16];
    const float* query_ln_w  = (const float*)d_in[17];
    const float* query_ln_b  = (const float*)d_in[18];
    const float* Wq          = (const float*)d_in[19];
    const float* bq          = (const float*)d_in[20];
    float* out = (float*)d_out;

    char* wsb = (char*)d_ws;
    unsigned short* x    = (unsigned short*)(wsb);              // 16,777,216
    unsigned short* hl   = (unsigned short*)(wsb + 16777216);   // 16,777,216
    unsigned short* Hb   = (unsigned short*)(wsb + 33554432);   // 33,554,432
    unsigned short* uu   = (unsigned short*)(wsb + 67108864);   // 6,291,456
    float* part          = (float*)(wsb + 73400320);            // 786,432
    unsigned short* w1T  = (unsigned short*)(wsb + 74188800);   // 2,097,152
    unsigned short* w2T  = (unsigned short*)(wsb + 76285952);   // 2,097,152
    unsigned short* wabcT= (unsigned short*)(wsb + 78383104);   // 196,608
    unsigned short* clsb = (unsigned short*)(wsb + 78579712);   // 24,576

    setup_kernel<<<6243, 256, 0, stream>>>(token_ids, tok_emb, pos_emb,
        stem_ln_w, stem_ln_b, x, hl,
        stem_w1, stem_w2, Wa, Wb, Wc, class_a, class_b, class_c,
        w1T, w2T, wabcT, clsb);

    for (int i = 0; i < 2; ++i) {
        if (i > 0)
            ln_kernel<<<NROWS / 4, 256, 0, stream>>>(x, stem_ln_w + 512, stem_ln_b + 512, hl);
        gemm_db<EPI_GELU_BF16, 128><<<dim3(128, 8), 256, 0, stream>>>(
            hl, 512, w1T + i * 524288, 512, stem_b1 + i * 1024, nullptr, Hb, 1024, 512);
        gemm_db<EPI_RES_BF16, 64><<<dim3(128, 8), 256, 0, stream>>>(
            Hb, 1024, w2T + i * 524288, 1024, stem_b2 + i * 512, x, x, 512, 1024);
    }

    ln_kernel<<<NROWS / 4, 256, 0, stream>>>(x, role_ln_w, role_ln_b, hl);

    tanh_class_kernel<<<dim3(128, 3), 256, 0, stream>>>(hl, wabcT, clsb, uu);

    scan_part_kernel<<<dim3(NB, 64), 64, 0, stream>>>(uu, part);

    float inv_denom = (float)(6.0 / (2047.0 * 2046.0 * 2045.0));
    combine_final_kernel<<<NB, 64, 0, stream>>>(part, x, query_ln_w, query_ln_b,
                                                Wq, bq, out, inv_denom);
}

// Round 3
// 340.401 us; speedup vs baseline: 1.0450x; 1.0072x over previous
//
#include <hip/hip_runtime.h>

#define NROWS 16384   // B*L
#define LSEQ  2048
#define NB    8

typedef short v8s __attribute__((ext_vector_type(8)));
typedef float v4f __attribute__((ext_vector_type(4)));

__device__ __forceinline__ unsigned short f2bf(float f) {
    unsigned int u = __float_as_uint(f);
    return (unsigned short)((u + 0x7fffu + ((u >> 16) & 1u)) >> 16);
}
__device__ __forceinline__ float bf2f(unsigned short u) {
    return __uint_as_float(((unsigned int)u) << 16);
}

// async global->LDS, 16B per lane; LDS dest is wave-uniform base + lane*16
__device__ __forceinline__ void glds16(const void* g, void* l) {
    __builtin_amdgcn_global_load_lds(
        (__attribute__((address_space(1))) void*)g,
        (__attribute__((address_space(3))) void*)l,
        16, 0, 0);
}

// fast exact-GELU: Abramowitz-Stegun 5-term erf, |err|<1.5e-7
__device__ __forceinline__ float fast_gelu(float v) {
    float z = fabsf(v) * 0.70710678118654752f;
    float t = __builtin_amdgcn_rcpf(1.0f + 0.3275911f * z);
    float poly = t * (0.254829592f + t * (-0.284496736f + t * (1.421413741f +
                 t * (-1.453152027f + t * 1.061405429f))));
    float erfz = 1.0f - poly * __expf(-z * z);
    float er = copysignf(erfz, v);
    return 0.5f * v * (1.0f + er);
}
__device__ __forceinline__ float fast_tanh(float y) {
    float e = __expf(2.0f * y);
    return (e - 1.0f) * __builtin_amdgcn_rcpf(e + 1.0f);
}

// XCD row-swizzle: block b (of 4096, 4 rows each) -> rows of 128-row tile T with
// T%8 == b%8, so the producer's XCD matches the GEMM reader's XCD (= (m>>7)%8).
__device__ __forceinline__ long swizzled_row(int b, int wave) {
    int T = (b & 7) + (((b >> 3) & 15) << 3);   // 0..127, T%8 == b%8
    int chunk = b >> 7;                          // 0..31
    return (long)T * 128 + chunk * 4 + wave;
}

// ------- merged setup: embed (blocks 0..4095, XCD-swizzled) | weight transposes
//         (4096..6239) | class converts (6240..6242); embed also emits LN0(hl) -------
__global__ __launch_bounds__(256) void setup_kernel(
        const int* __restrict__ ids,
        const float* __restrict__ tok, const float* __restrict__ pos,
        const float* __restrict__ g0, const float* __restrict__ b0,
        unsigned short* __restrict__ x, unsigned short* __restrict__ hl,
        const float* __restrict__ w1, const float* __restrict__ w2,
        const float* __restrict__ wa, const float* __restrict__ wb, const float* __restrict__ wc,
        const float* __restrict__ ca, const float* __restrict__ cb, const float* __restrict__ cc,
        unsigned short* __restrict__ w1T, unsigned short* __restrict__ w2T,
        unsigned short* __restrict__ wabcT, unsigned short* __restrict__ clsb) {
    int blk = blockIdx.x;
    int t = threadIdx.x;
    if (blk < 4096) {
        int wave = t >> 6, lane = t & 63;
        long row = swizzled_row(blk, wave);
        int l = (int)(row & (LSEQ - 1));
        int id = ids[row];
        int d = lane * 8;
        float4 t0 = *(const float4*)(tok + (size_t)id * 512 + d);
        float4 t1 = *(const float4*)(tok + (size_t)id * 512 + d + 4);
        float4 p0 = *(const float4*)(pos + (size_t)l * 512 + d);
        float4 p1 = *(const float4*)(pos + (size_t)l * 512 + d + 4);
        float a[8] = {t0.x + p0.x, t0.y + p0.y, t0.z + p0.z, t0.w + p0.w,
                      t1.x + p1.x, t1.y + p1.y, t1.z + p1.z, t1.w + p1.w};
        unsigned int xp[4];
        #pragma unroll
        for (int i = 0; i < 4; ++i)
            xp[i] = (unsigned int)f2bf(a[2 * i]) | ((unsigned int)f2bf(a[2 * i + 1]) << 16);
        *(uint4*)(x + row * 512 + d) = *(uint4*)xp;
        float s = 0.f, s2 = 0.f;
        #pragma unroll
        for (int i = 0; i < 8; ++i) { s += a[i]; s2 += a[i] * a[i]; }
        #pragma unroll
        for (int o = 32; o > 0; o >>= 1) { s += __shfl_down(s, o); s2 += __shfl_down(s2, o); }
        s = __shfl(s, 0); s2 = __shfl(s2, 0);
        float m = s * (1.0f / 512.0f);
        float rinv = 1.0f / sqrtf(s2 * (1.0f / 512.0f) - m * m + 1e-5f);
        float4 ga = *(const float4*)(g0 + d), gb = *(const float4*)(g0 + d + 4);
        float4 ba = *(const float4*)(b0 + d), bb2 = *(const float4*)(b0 + d + 4);
        float gg[8] = {ga.x, ga.y, ga.z, ga.w, gb.x, gb.y, gb.z, gb.w};
        float bb[8] = {ba.x, ba.y, ba.z, ba.w, bb2.x, bb2.y, bb2.z, bb2.w};
        unsigned int hp[4];
        #pragma unroll
        for (int i = 0; i < 4; ++i) {
            unsigned short lo = f2bf((a[2 * i]     - m) * rinv * gg[2 * i]     + bb[2 * i]);
            unsigned short hi = f2bf((a[2 * i + 1] - m) * rinv * gg[2 * i + 1] + bb[2 * i + 1]);
            hp[i] = (unsigned int)lo | ((unsigned int)hi << 16);
        }
        *(uint4*)(hl + row * 512 + d) = *(uint4*)hp;
    } else if (blk < 6240) {
        int id = blk - 4096;
        int tx = t & 31, ty = t >> 5;
        const float* in; unsigned short* out; int R, C, bx, by, ldo;
        if (id < 1024) {
            int l = id >> 9, r = id & 511;
            in = w1 + l * 524288; out = w1T + l * 524288;
            R = 512; C = 1024; bx = r & 31; by = r >> 5; ldo = 512;
        } else if (id < 2048) {
            int l = (id - 1024) >> 9, r = (id - 1024) & 511;
            in = w2 + l * 524288; out = w2T + l * 524288;
            R = 1024; C = 512; bx = r & 15; by = r >> 4; ldo = 1024;
        } else {
            int g = (id - 2048) >> 5, r = (id - 2048) & 31;
            in = (g == 0) ? wa : (g == 1) ? wb : wc;
            out = wabcT + g * 32768;
            R = 512; C = 64; bx = r & 1; by = r >> 1; ldo = 512;
        }
        __shared__ unsigned short tile[32][33];
        int c0 = bx * 32, r0 = by * 32;
        for (int i = ty; i < 32; i += 8) {
            int r = r0 + i, c = c0 + tx;
            tile[i][tx] = (r < R && c < C) ? f2bf(in[(size_t)r * C + c]) : (unsigned short)0;
        }
        __syncthreads();
        for (int i = ty; i < 32; i += 8) {
            int c = c0 + i, r = r0 + tx;
            if (r < R && c < C) out[(size_t)c * ldo + r] = tile[tx][i];
        }
    } else {
        int g = blk - 6240;
        const float* src = (g == 0) ? ca : (g == 1) ? cb : cc;
        unsigned short* dst = clsb + g * 4096;
        for (int i = t; i < 4096; i += 256) dst[i] = f2bf(src[i]);
    }
}

// ------- LayerNorm, one wave per row, XCD-swizzled block->row mapping -------
__global__ __launch_bounds__(256) void ln_kernel(const unsigned short* __restrict__ x,
        const float* __restrict__ g, const float* __restrict__ b,
        unsigned short* __restrict__ out) {
    int wave = threadIdx.x >> 6, lane = threadIdx.x & 63;
    long row = swizzled_row(blockIdx.x, wave);
    int d = lane * 8;
    uint4 xp = *(const uint4*)(x + row * 512 + d);
    const unsigned int* xw = (const unsigned int*)&xp;
    float a[8];
    #pragma unroll
    for (int i = 0; i < 4; ++i) {
        a[2 * i]     = bf2f((unsigned short)(xw[i] & 0xffff));
        a[2 * i + 1] = bf2f((unsigned short)(xw[i] >> 16));
    }
    float s = 0.f, s2 = 0.f;
    #pragma unroll
    for (int i = 0; i < 8; ++i) { s += a[i]; s2 += a[i] * a[i]; }
    #pragma unroll
    for (int o = 32; o > 0; o >>= 1) { s += __shfl_down(s, o); s2 += __shfl_down(s2, o); }
    s = __shfl(s, 0); s2 = __shfl(s2, 0);
    float m = s * (1.0f / 512.0f);
    float rinv = 1.0f / sqrtf(s2 * (1.0f / 512.0f) - m * m + 1e-5f);
    float4 g0 = *(const float4*)(g + d), g1 = *(const float4*)(g + d + 4);
    float4 b0 = *(const float4*)(b + d), b1 = *(const float4*)(b + d + 4);
    float gg[8] = {g0.x, g0.y, g0.z, g0.w, g1.x, g1.y, g1.z, g1.w};
    float bb[8] = {b0.x, b0.y, b0.z, b0.w, b1.x, b1.y, b1.z, b1.w};
    unsigned int hp[4];
    #pragma unroll
    for (int i = 0; i < 4; ++i) {
        unsigned short lo = f2bf((a[2 * i]     - m) * rinv * gg[2 * i]     + bb[2 * i]);
        unsigned short hi = f2bf((a[2 * i + 1] - m) * rinv * gg[2 * i + 1] + bb[2 * i + 1]);
        hp[i] = (unsigned int)lo | ((unsigned int)hi << 16);
    }
    *(uint4*)(out + row * 512 + d) = *(uint4*)hp;
}

// ------- MFMA GEMM: triple-buffered global_load_lds, prefetch distance 2,
//         counted vmcnt, raw barriers -------
#define EPI_GELU_BF16  0
#define EPI_RES_BF16   1

template <int EPI, int TN>
__global__ __launch_bounds__(256) void gemm_db(
        const unsigned short* __restrict__ A, int lda,
        const unsigned short* __restrict__ BT, int ldb,
        const float* __restrict__ bias,
        const unsigned short* __restrict__ xres,
        unsigned short* __restrict__ Cout, int ldc, int K) {
    constexpr int NJ = TN / 32;          // acc cols per wave
    constexpr int BCH = TN / 64;         // B staging chunks per wave (128->2, 64->1)
    constexpr int NL = 2 + BCH;          // glds16 per wave per K-tile
    // LINEAR layouts (no padding) — required by global_load_lds lane mapping
    __shared__ unsigned short As[3][128 * 32] __attribute__((aligned(16)));
    __shared__ unsigned short Bs[3][TN * 32] __attribute__((aligned(16)));
    const int t = threadIdx.x;
    const int lane = t & 63, wave = t >> 6;
    const int quad = lane >> 4, l16 = lane & 15;
    const int wm = (wave >> 1) * 64, wn = (wave & 1) * (TN / 2);
    const long tileM = (long)blockIdx.x * 128, tileN = (long)blockIdx.y * TN;

    // staging: chunk = 16 rows x 32 cols (1 KiB). lane l -> row +l/4, col (l&3)*8
    const int lr = lane >> 2, lc = (lane & 3) * 8;
    const unsigned short* gA0 = A + (tileM + wave * 32 + lr) * (size_t)lda + lc;
    const unsigned short* gA1 = gA0 + 16 * (size_t)lda;
    const unsigned short* gB0 = BT + (tileN + wave * (BCH * 16) + lr) * (size_t)ldb + lc;
    const unsigned short* gB1 = gB0 + 16 * (size_t)ldb;

    v4f acc[4][NJ] = {};

    auto stage = [&](unsigned short* ab, unsigned short* bb) {
        glds16(gA0, ab + wave * 1024);
        glds16(gA1, ab + wave * 1024 + 512);
        glds16(gB0, bb + wave * (BCH * 512));
        if constexpr (BCH == 2) glds16(gB1, bb + wave * 1024 + 512);
        gA0 += 32; gA1 += 32; gB0 += 32;
        if constexpr (BCH == 2) gB1 += 32;
    };

    unsigned short *a0 = As[0], *a1 = As[1], *a2 = As[2];
    unsigned short *b0 = Bs[0], *b1 = Bs[1], *b2 = Bs[2];

    stage(a0, b0);                        // tile 0 in flight
    stage(a1, b1);                        // tile 1 in flight

    const int nk = K >> 5;
    for (int kk = 0; kk < nk; ++kk) {
        if (kk + 2 < nk) {
            stage(a2, b2);                // issue tile kk+2; 3 tiles now in flight max
            asm volatile("s_waitcnt vmcnt(%0)" :: "i"(2 * NL) : "memory");
        } else if (kk + 1 < nk) {
            asm volatile("s_waitcnt vmcnt(%0)" :: "i"(NL) : "memory");
        } else {
            asm volatile("s_waitcnt vmcnt(0)" ::: "memory");
        }
        asm volatile("s_barrier" ::: "memory");   // raw: no compiler vmcnt(0) drain
        v8s af[4], bfr[NJ];
        #pragma unroll
        for (int i = 0; i < 4; ++i)
            af[i] = *(const v8s*)(a0 + (wm + i * 16 + l16) * 32 + quad * 8);
        #pragma unroll
        for (int j = 0; j < NJ; ++j)
            bfr[j] = *(const v8s*)(b0 + (wn + j * 16 + l16) * 32 + quad * 8);
        #pragma unroll
        for (int i = 0; i < 4; ++i)
            #pragma unroll
            for (int j = 0; j < NJ; ++j)
                acc[i][j] = __builtin_amdgcn_mfma_f32_16x16x32_bf16(bfr[j], af[i], acc[i][j], 0, 0, 0);
        if (kk + 1 < nk)
            asm volatile("s_barrier" ::: "memory");  // all reads of this buf done before restage
        unsigned short* ta = a0; a0 = a1; a1 = a2; a2 = ta;
        unsigned short* tb = b0; b0 = b1; b1 = b2; b2 = tb;
    }

    // packed epilogue: fixed m per lane, 4 consecutive n per acc
    #pragma unroll
    for (int i = 0; i < 4; ++i) {
        long m = tileM + wm + i * 16 + l16;
        #pragma unroll
        for (int j = 0; j < NJ; ++j) {
            long n0 = tileN + wn + j * 16 + quad * 4;
            float4 bi = *(const float4*)&bias[n0];
            const float* bip = (const float*)&bi;
            unsigned short pk[4];
            if (EPI == EPI_GELU_BF16) {
                #pragma unroll
                for (int r = 0; r < 4; ++r)
                    pk[r] = f2bf(fast_gelu(acc[i][j][r] + bip[r]));
            } else {
                ushort4 xr4 = *(const ushort4*)&xres[m * ldc + n0];
                const unsigned short* xp = (const unsigned short*)&xr4;
                #pragma unroll
                for (int r = 0; r < 4; ++r)
                    pk[r] = f2bf(acc[i][j][r] + bip[r] + bf2f(xp[r]));
            }
            *(ushort4*)&Cout[m * ldc + n0] = *(ushort4*)pk;
        }
    }
}

// ------- fused tanh-GEMM + class-GEMM, R2-structure K-loop, TM=128 -------
// (reverted to the round-0 reg-staged structure: rounds 1-2 glds conversions
//  cost ~50 µs in the non-top-5 total; direct cross-round A/B evidence)
__global__ __launch_bounds__(256) void tanh_class_kernel(
        const unsigned short* __restrict__ A,
        const unsigned short* __restrict__ WT,
        const unsigned short* __restrict__ cls,
        unsigned short* __restrict__ uu) {
    __shared__ unsigned short As[128][40] __attribute__((aligned(16)));
    __shared__ unsigned short Bs[64][40] __attribute__((aligned(16)));
    __shared__ unsigned short P[128 * 72] __attribute__((aligned(16)));
    const int t = threadIdx.x;
    const int lane = t & 63, wave = t >> 6;
    const int quad = lane >> 4, l16 = lane & 15;
    const int wm = (wave >> 1) * 64, wn = (wave & 1) * 32;
    const long tileM = (long)blockIdx.x * 128;
    const int g = blockIdx.y;
    const int arow = t >> 2, acol = (t & 3) * 8;

    const unsigned short* BT = WT + g * 32768;
    v8s cf[2][2];
    #pragma unroll
    for (int ks = 0; ks < 2; ++ks)
        #pragma unroll
        for (int j = 0; j < 2; ++j)
            cf[ks][j] = *(const v8s*)&cls[g * 4096 + (wn + j * 16 + l16) * 64 + ks * 32 + quad * 8];

    const unsigned short* gA0 = A + (tileM + arow) * 512 + acol;
    const unsigned short* gA1 = gA0 + 64 * 512;
    const unsigned short* gB0 = BT + arow * 512 + acol;

    v4f acc[4][2] = {};
    uint4 a0, a1, b0;
    a0 = *(const uint4*)gA0; a1 = *(const uint4*)gA1; gA0 += 32; gA1 += 32;
    b0 = *(const uint4*)gB0; gB0 += 32;
    *(uint4*)&As[arow][acol] = a0;
    *(uint4*)&As[arow + 64][acol] = a1;
    *(uint4*)&Bs[arow][acol] = b0;

    for (int kk = 0; kk < 16; ++kk) {
        __syncthreads();
        const bool more = kk < 15;
        if (more) {
            a0 = *(const uint4*)gA0; a1 = *(const uint4*)gA1; gA0 += 32; gA1 += 32;
            b0 = *(const uint4*)gB0; gB0 += 32;
        }
        v8s af[4], bfr[2];
        #pragma unroll
        for (int i = 0; i < 4; ++i) af[i] = *(const v8s*)&As[wm + i * 16 + l16][quad * 8];
        #pragma unroll
        for (int j = 0; j < 2; ++j) bfr[j] = *(const v8s*)&Bs[wn + j * 16 + l16][quad * 8];
        #pragma unroll
        for (int i = 0; i < 4; ++i)
            #pragma unroll
            for (int j = 0; j < 2; ++j)
                acc[i][j] = __builtin_amdgcn_mfma_f32_16x16x32_bf16(bfr[j], af[i], acc[i][j], 0, 0, 0);
        __syncthreads();
        if (more) {
            *(uint4*)&As[arow][acol] = a0;
            *(uint4*)&As[arow + 64][acol] = a1;
            *(uint4*)&Bs[arow][acol] = b0;
        }
    }

    #pragma unroll
    for (int i = 0; i < 4; ++i) {
        int m = wm + i * 16 + l16;
        #pragma unroll
        for (int j = 0; j < 2; ++j) {
            int n0 = wn + j * 16 + quad * 4;
            unsigned short pk[4];
            #pragma unroll
            for (int r = 0; r < 4; ++r) pk[r] = f2bf(fast_tanh(acc[i][j][r]));
            *(ushort4*)&P[m * 72 + n0] = *(ushort4*)pk;
        }
    }
    __syncthreads();

    v4f acc2[4][2] = {};
    #pragma unroll
    for (int ks = 0; ks < 2; ++ks) {
        v8s paf[4];
        #pragma unroll
        for (int i = 0; i < 4; ++i)
            paf[i] = *(const v8s*)&P[(wm + i * 16 + l16) * 72 + ks * 32 + quad * 8];
        #pragma unroll
        for (int i = 0; i < 4; ++i)
            #pragma unroll
            for (int j = 0; j < 2; ++j)
                acc2[i][j] = __builtin_amdgcn_mfma_f32_16x16x32_bf16(cf[ks][j], paf[i], acc2[i][j], 0, 0, 0);
    }

    #pragma unroll
    for (int i = 0; i < 4; ++i) {
        long m = tileM + wm + i * 16 + l16;
        #pragma unroll
        for (int j = 0; j < 2; ++j) {
            int c0 = wn + j * 16 + quad * 4;
            unsigned short pk[4];
            #pragma unroll
            for (int r = 0; r < 4; ++r) pk[r] = f2bf(acc2[i][j][r]);
            *(ushort4*)&uu[m * 192 + g * 64 + c0] = *(ushort4*)pk;
        }
    }
}

// ------- exact ordered-triplet scan pass 1 -------
__global__ __launch_bounds__(64) void scan_part_kernel(const unsigned short* __restrict__ u,
                                                       float* __restrict__ part) {
    int b = blockIdx.x, seg = blockIdx.y;
    int c = threadIdx.x;
    int l0 = seg * 32;
    int l1 = l0 + 32; if (l1 > 2047) l1 = 2047;
    float sA = 0.f, sB = 0.f, sC = 0.f, T = 0.f, M = 0.f, U = 0.f;
    const unsigned short* base = u + ((size_t)b * LSEQ + l0) * 192 + c;
    for (int l = l0; l < l1; ++l) {
        float ua = bf2f(base[0]), ub = bf2f(base[64]), uc = bf2f(base[128]);
        base += 192;
        U += uc * T;
        M += uc * sB;
        T += ub * sA;
        sA += ua; sB += ub; sC += uc;
    }
    float* p = part + ((size_t)(b * 64 + seg)) * 384 + c;
    p[0] = sA; p[64] = sB; p[128] = sC; p[192] = T; p[256] = M; p[320] = U;
}

// ------- merged: segment combine + final LN + Wq GEMV -------
__global__ __launch_bounds__(64) void combine_final_kernel(const float* __restrict__ part,
        const unsigned short* __restrict__ x,
        const float* __restrict__ qw, const float* __restrict__ qb,
        const float* __restrict__ Wq, const float* __restrict__ bq,
        float* __restrict__ out, float inv_denom) {
    int b = blockIdx.x;
    int c = threadIdx.x;
    const float* p = part + (size_t)b * 64 * 384 + c;
    float A = p[0], B = p[64], Tt = p[192], Mt = p[256], Ut = p[320];
    for (int seg = 1; seg < 64; ++seg) {
        const float* q2 = p + seg * 384;
        float a2 = q2[0], b2 = q2[64], c2 = q2[128], t2 = q2[192], m2 = q2[256], u2 = q2[320];
        float Un = Ut + u2 + c2 * Tt + A * m2;
        float Tn = Tt + t2 + A * b2;
        float Mn = Mt + m2 + B * c2;
        A += a2; B += b2;
        Ut = Un; Tt = Tn; Mt = Mn;
    }
    __shared__ float q[512];
    __shared__ float mv[2];
    const unsigned short* xr = x + ((size_t)b * LSEQ + (LSEQ - 1)) * 512;
    float s1 = 0.f, s2 = 0.f;
    for (int i = c; i < 512; i += 64) { float v = bf2f(xr[i]); q[i] = v; s1 += v; s2 += v * v; }
    #pragma unroll
    for (int o = 32; o > 0; o >>= 1) { s1 += __shfl_down(s1, o); s2 += __shfl_down(s2, o); }
    if (c == 0) {
        float m = s1 * (1.0f / 512.0f);
        float var = s2 * (1.0f / 512.0f) - m * m;
        mv[0] = m; mv[1] = 1.0f / sqrtf(var + 1e-5f);
    }
    __syncthreads();
    float m = mv[0], r = mv[1];
    for (int i = c; i < 512; i += 64) q[i] = (q[i] - m) * r * qw[i] + qb[i];
    __syncthreads();
    float acc = 0.f;
    for (int d = 0; d < 512; ++d) acc += q[d] * Wq[d * 64 + c];
    out[b * 64 + c] = Ut * inv_denom + acc + bq[c];
}

extern "C" void kernel_launch(void* const* d_in, const int* in_sizes, int n_in,
                              void* d_out, int out_size, void* d_ws, size_t ws_size,
                              hipStream_t stream) {
    const int*   token_ids   = (const int*)d_in[0];
    const float* tok_emb     = (const float*)d_in[1];
    const float* pos_emb     = (const float*)d_in[2];
    const float* stem_ln_w   = (const float*)d_in[3];
    const float* stem_ln_b   = (const float*)d_in[4];
    const float* stem_w1     = (const float*)d_in[5];
    const float* stem_b1     = (const float*)d_in[6];
    const float* stem_w2     = (const float*)d_in[7];
    const float* stem_b2     = (const float*)d_in[8];
    const float* role_ln_w   = (const float*)d_in[9];
    const float* role_ln_b   = (const float*)d_in[10];
    const float* Wa          = (const float*)d_in[11];
    const float* Wb          = (const float*)d_in[12];
    const float* Wc          = (const float*)d_in[13];
    const float* class_a     = (const float*)d_in[14];
    const float* class_b     = (const float*)d_in[15];
    const float* class_c     = (const float*)d_in[16];
    const float* query_ln_w  = (const float*)d_in[17];
    const float* query_ln_b  = (const float*)d_in[18];
    const float* Wq          = (const float*)d_in[19];
    const float* bq          = (const float*)d_in[20];
    float* out = (float*)d_out;

    char* wsb = (char*)d_ws;
    unsigned short* x    = (unsigned short*)(wsb);              // 16,777,216
    unsigned short* hl   = (unsigned short*)(wsb + 16777216);   // 16,777,216
    unsigned short* Hb   = (unsigned short*)(wsb + 33554432);   // 33,554,432
    unsigned short* uu   = (unsigned short*)(wsb + 67108864);   // 6,291,456
    float* part          = (float*)(wsb + 73400320);            // 786,432
    unsigned short* w1T  = (unsigned short*)(wsb + 74188800);   // 2,097,152
    unsigned short* w2T  = (unsigned short*)(wsb + 76285952);   // 2,097,152
    unsigned short* wabcT= (unsigned short*)(wsb + 78383104);   // 196,608
    unsigned short* clsb = (unsigned short*)(wsb + 78579712);   // 24,576

    setup_kernel<<<6243, 256, 0, stream>>>(token_ids, tok_emb, pos_emb,
        stem_ln_w, stem_ln_b, x, hl,
        stem_w1, stem_w2, Wa, Wb, Wc, class_a, class_b, class_c,
        w1T, w2T, wabcT, clsb);

    for (int i = 0; i < 2; ++i) {
        if (i > 0)
            ln_kernel<<<NROWS / 4, 256, 0, stream>>>(x, stem_ln_w + 512, stem_ln_b + 512, hl);
        gemm_db<EPI_GELU_BF16, 128><<<dim3(128, 8), 256, 0, stream>>>(
            hl, 512, w1T + i * 524288, 512, stem_b1 + i * 1024, nullptr, Hb, 1024, 512);
        gemm_db<EPI_RES_BF16, 64><<<dim3(128, 8), 256, 0, stream>>>(
            Hb, 1024, w2T + i * 524288, 1024, stem_b2 + i * 512, x, x, 512, 1024);
    }

    ln_kernel<<<NROWS / 4, 256, 0, stream>>>(x, role_ln_w, role_ln_b, hl);

    tanh_class_kernel<<<dim3(128, 3), 256, 0, stream>>>(hl, wabcT, clsb, uu);

    scan_part_kernel<<<dim3(NB, 64), 64, 0, stream>>>(uu, part);

    float inv_denom = (float)(6.0 / (2047.0 * 2046.0 * 2045.0));
    combine_final_kernel<<<NB, 64, 0, stream>>>(part, x, query_ln_w, query_ln_b,
                                                Wq, bq, out, inv_denom);
}

// Round 4
// 337.132 us; speedup vs baseline: 1.0551x; 1.0097x over previous
//
#include <hip/hip_runtime.h>

#define NROWS 16384   // B*L
#define LSEQ  2048
#define NB    8

typedef short v8s __attribute__((ext_vector_type(8)));
typedef float v4f __attribute__((ext_vector_type(4)));

__device__ __forceinline__ unsigned short f2bf(float f) {
    unsigned int u = __float_as_uint(f);
    return (unsigned short)((u + 0x7fffu + ((u >> 16) & 1u)) >> 16);
}
__device__ __forceinline__ float bf2f(unsigned short u) {
    return __uint_as_float(((unsigned int)u) << 16);
}

// async global->LDS, 16B per lane; LDS dest is wave-uniform base + lane*16
__device__ __forceinline__ void glds16(const void* g, void* l) {
    __builtin_amdgcn_global_load_lds(
        (__attribute__((address_space(1))) void*)g,
        (__attribute__((address_space(3))) void*)l,
        16, 0, 0);
}

// 16B-chunk LDS swizzle (involution): c = 4*row + slot within a [R][32]-bf16
// tile. XOR row bits 1..3 into {slot bits, row bit 0} so each 16-lane read
// phase spreads over all 8 bank-groups (2 lanes/bank = free). Applied to
// BOTH the global staging source and the LDS read offsets (rule #21);
// glds16 dest stays linear.
__device__ __forceinline__ int swz(int c) {
    return c ^ ((((c >> 3) & 1) << 1) | (((c >> 4) & 1) << 2) | ((c >> 5) & 1));
}

// fast exact-GELU: Abramowitz-Stegun 5-term erf, |err|<1.5e-7
__device__ __forceinline__ float fast_gelu(float v) {
    float z = fabsf(v) * 0.70710678118654752f;
    float t = __builtin_amdgcn_rcpf(1.0f + 0.3275911f * z);
    float poly = t * (0.254829592f + t * (-0.284496736f + t * (1.421413741f +
                 t * (-1.453152027f + t * 1.061405429f))));
    float erfz = 1.0f - poly * __expf(-z * z);
    float er = copysignf(erfz, v);
    return 0.5f * v * (1.0f + er);
}
__device__ __forceinline__ float fast_tanh(float y) {
    float e = __expf(2.0f * y);
    return (e - 1.0f) * __builtin_amdgcn_rcpf(e + 1.0f);
}

// XCD row-swizzle: block b (of 4096, 4 rows each) -> rows of 128-row tile T with
// T%8 == b%8, so the producer's XCD matches the GEMM reader's XCD (= (m>>7)%8).
__device__ __forceinline__ long swizzled_row(int b, int wave) {
    int T = (b & 7) + (((b >> 3) & 15) << 3);   // 0..127, T%8 == b%8
    int chunk = b >> 7;                          // 0..31
    return (long)T * 128 + chunk * 4 + wave;
}

// ------- merged setup: embed (blocks 0..4095, XCD-swizzled) | weight transposes
//         (4096..6239) | class converts (6240..6242); embed also emits LN0(hl) -------
__global__ __launch_bounds__(256) void setup_kernel(
        const int* __restrict__ ids,
        const float* __restrict__ tok, const float* __restrict__ pos,
        const float* __restrict__ g0, const float* __restrict__ b0,
        unsigned short* __restrict__ x, unsigned short* __restrict__ hl,
        const float* __restrict__ w1, const float* __restrict__ w2,
        const float* __restrict__ wa, const float* __restrict__ wb, const float* __restrict__ wc,
        const float* __restrict__ ca, const float* __restrict__ cb, const float* __restrict__ cc,
        unsigned short* __restrict__ w1T, unsigned short* __restrict__ w2T,
        unsigned short* __restrict__ wabcT, unsigned short* __restrict__ clsb) {
    int blk = blockIdx.x;
    int t = threadIdx.x;
    if (blk < 4096) {
        int wave = t >> 6, lane = t & 63;
        long row = swizzled_row(blk, wave);
        int l = (int)(row & (LSEQ - 1));
        int id = ids[row];
        int d = lane * 8;
        float4 t0 = *(const float4*)(tok + (size_t)id * 512 + d);
        float4 t1 = *(const float4*)(tok + (size_t)id * 512 + d + 4);
        float4 p0 = *(const float4*)(pos + (size_t)l * 512 + d);
        float4 p1 = *(const float4*)(pos + (size_t)l * 512 + d + 4);
        float a[8] = {t0.x + p0.x, t0.y + p0.y, t0.z + p0.z, t0.w + p0.w,
                      t1.x + p1.x, t1.y + p1.y, t1.z + p1.z, t1.w + p1.w};
        unsigned int xp[4];
        #pragma unroll
        for (int i = 0; i < 4; ++i)
            xp[i] = (unsigned int)f2bf(a[2 * i]) | ((unsigned int)f2bf(a[2 * i + 1]) << 16);
        *(uint4*)(x + row * 512 + d) = *(uint4*)xp;
        float s = 0.f, s2 = 0.f;
        #pragma unroll
        for (int i = 0; i < 8; ++i) { s += a[i]; s2 += a[i] * a[i]; }
        #pragma unroll
        for (int o = 32; o > 0; o >>= 1) { s += __shfl_down(s, o); s2 += __shfl_down(s2, o); }
        s = __shfl(s, 0); s2 = __shfl(s2, 0);
        float m = s * (1.0f / 512.0f);
        float rinv = 1.0f / sqrtf(s2 * (1.0f / 512.0f) - m * m + 1e-5f);
        float4 ga = *(const float4*)(g0 + d), gb = *(const float4*)(g0 + d + 4);
        float4 ba = *(const float4*)(b0 + d), bb2 = *(const float4*)(b0 + d + 4);
        float gg[8] = {ga.x, ga.y, ga.z, ga.w, gb.x, gb.y, gb.z, gb.w};
        float bb[8] = {ba.x, ba.y, ba.z, ba.w, bb2.x, bb2.y, bb2.z, bb2.w};
        unsigned int hp[4];
        #pragma unroll
        for (int i = 0; i < 4; ++i) {
            unsigned short lo = f2bf((a[2 * i]     - m) * rinv * gg[2 * i]     + bb[2 * i]);
            unsigned short hi = f2bf((a[2 * i + 1] - m) * rinv * gg[2 * i + 1] + bb[2 * i + 1]);
            hp[i] = (unsigned int)lo | ((unsigned int)hi << 16);
        }
        *(uint4*)(hl + row * 512 + d) = *(uint4*)hp;
    } else if (blk < 6240) {
        int id = blk - 4096;
        int tx = t & 31, ty = t >> 5;
        const float* in; unsigned short* out; int R, C, bx, by, ldo;
        if (id < 1024) {
            int l = id >> 9, r = id & 511;
            in = w1 + l * 524288; out = w1T + l * 524288;
            R = 512; C = 1024; bx = r & 31; by = r >> 5; ldo = 512;
        } else if (id < 2048) {
            int l = (id - 1024) >> 9, r = (id - 1024) & 511;
            in = w2 + l * 524288; out = w2T + l * 524288;
            R = 1024; C = 512; bx = r & 15; by = r >> 4; ldo = 1024;
        } else {
            int g = (id - 2048) >> 5, r = (id - 2048) & 31;
            in = (g == 0) ? wa : (g == 1) ? wb : wc;
            out = wabcT + g * 32768;
            R = 512; C = 64; bx = r & 1; by = r >> 1; ldo = 512;
        }
        __shared__ unsigned short tile[32][33];
        int c0 = bx * 32, r0 = by * 32;
        for (int i = ty; i < 32; i += 8) {
            int r = r0 + i, c = c0 + tx;
            tile[i][tx] = (r < R && c < C) ? f2bf(in[(size_t)r * C + c]) : (unsigned short)0;
        }
        __syncthreads();
        for (int i = ty; i < 32; i += 8) {
            int c = c0 + i, r = r0 + tx;
            if (r < R && c < C) out[(size_t)c * ldo + r] = tile[tx][i];
        }
    } else {
        int g = blk - 6240;
        const float* src = (g == 0) ? ca : (g == 1) ? cb : cc;
        unsigned short* dst = clsb + g * 4096;
        for (int i = t; i < 4096; i += 256) dst[i] = f2bf(src[i]);
    }
}

// ------- LayerNorm, one wave per row, XCD-swizzled block->row mapping -------
__global__ __launch_bounds__(256) void ln_kernel(const unsigned short* __restrict__ x,
        const float* __restrict__ g, const float* __restrict__ b,
        unsigned short* __restrict__ out) {
    int wave = threadIdx.x >> 6, lane = threadIdx.x & 63;
    long row = swizzled_row(blockIdx.x, wave);
    int d = lane * 8;
    uint4 xp = *(const uint4*)(x + row * 512 + d);
    const unsigned int* xw = (const unsigned int*)&xp;
    float a[8];
    #pragma unroll
    for (int i = 0; i < 4; ++i) {
        a[2 * i]     = bf2f((unsigned short)(xw[i] & 0xffff));
        a[2 * i + 1] = bf2f((unsigned short)(xw[i] >> 16));
    }
    float s = 0.f, s2 = 0.f;
    #pragma unroll
    for (int i = 0; i < 8; ++i) { s += a[i]; s2 += a[i] * a[i]; }
    #pragma unroll
    for (int o = 32; o > 0; o >>= 1) { s += __shfl_down(s, o); s2 += __shfl_down(s2, o); }
    s = __shfl(s, 0); s2 = __shfl(s2, 0);
    float m = s * (1.0f / 512.0f);
    float rinv = 1.0f / sqrtf(s2 * (1.0f / 512.0f) - m * m + 1e-5f);
    float4 g0 = *(const float4*)(g + d), g1 = *(const float4*)(g + d + 4);
    float4 b0 = *(const float4*)(b + d), b1 = *(const float4*)(b + d + 4);
    float gg[8] = {g0.x, g0.y, g0.z, g0.w, g1.x, g1.y, g1.z, g1.w};
    float bb[8] = {b0.x, b0.y, b0.z, b0.w, b1.x, b1.y, b1.z, b1.w};
    unsigned int hp[4];
    #pragma unroll
    for (int i = 0; i < 4; ++i) {
        unsigned short lo = f2bf((a[2 * i]     - m) * rinv * gg[2 * i]     + bb[2 * i]);
        unsigned short hi = f2bf((a[2 * i + 1] - m) * rinv * gg[2 * i + 1] + bb[2 * i + 1]);
        hp[i] = (unsigned int)lo | ((unsigned int)hi << 16);
    }
    *(uint4*)(out + row * 512 + d) = *(uint4*)hp;
}

// ------- MFMA GEMM: double-buffered global_load_lds + chunk-XOR bank swizzle,
//         counted vmcnt, raw barriers -------
#define EPI_GELU_BF16  0
#define EPI_RES_BF16   1

template <int EPI, int TN>
__global__ __launch_bounds__(256) void gemm_swz(
        const unsigned short* __restrict__ A, int lda,
        const unsigned short* __restrict__ BT, int ldb,
        const float* __restrict__ bias,
        const unsigned short* __restrict__ xres,
        unsigned short* __restrict__ Cout, int ldc, int K) {
    constexpr int NJ = TN / 32;          // acc cols per wave
    constexpr int BCH = TN / 64;         // B staging chunks per wave (128->2, 64->1)
    constexpr int NL = 2 + BCH;          // glds16 per wave per K-tile
    // LINEAR layouts (no padding) — required by global_load_lds lane mapping
    __shared__ unsigned short As[2][128 * 32] __attribute__((aligned(16)));
    __shared__ unsigned short Bs[2][TN * 32] __attribute__((aligned(16)));
    const int t = threadIdx.x;
    const int lane = t & 63, wave = t >> 6;
    const int quad = lane >> 4, l16 = lane & 15;
    const int wm = (wave >> 1) * 64, wn = (wave & 1) * (TN / 2);
    const long tileM = (long)blockIdx.x * 128, tileN = (long)blockIdx.y * TN;

    // ---- staging sources: LDS chunk c (linear, = wave-region + lane) receives
    //      global chunk swz(c). row/slot per lane are loop-invariant. ----
    const int cA0 = wave * 128 + lane;               // A chunks: wave covers 128
    const int gA0c = swz(cA0), gA1c = swz(cA0 + 64);
    const unsigned short* gA0 = A + (tileM + (gA0c >> 2)) * (size_t)lda + (gA0c & 3) * 8;
    const unsigned short* gA1 = A + (tileM + (gA1c >> 2)) * (size_t)lda + (gA1c & 3) * 8;
    const int cB0 = wave * (BCH * 64) + lane;
    const int gB0c = swz(cB0);
    const unsigned short* gB0 = BT + (tileN + (gB0c >> 2)) * (size_t)ldb + (gB0c & 3) * 8;
    const unsigned short* gB1 = nullptr;
    if constexpr (BCH == 2) {
        const int gB1c = swz(cB0 + 64);
        gB1 = BT + (tileN + (gB1c >> 2)) * (size_t)ldb + (gB1c & 3) * 8;
    }

    // ---- swizzled read offsets (shorts), loop-invariant ----
    int aoff[4], boff[NJ];
    #pragma unroll
    for (int i = 0; i < 4; ++i) aoff[i] = swz((wm + i * 16 + l16) * 4 + quad) * 8;
    #pragma unroll
    for (int j = 0; j < NJ; ++j) boff[j] = swz((wn + j * 16 + l16) * 4 + quad) * 8;

    v4f acc[4][NJ] = {};

    auto stage = [&](int buf) {
        glds16(gA0, &As[buf][wave * 1024]);
        glds16(gA1, &As[buf][wave * 1024 + 512]);
        glds16(gB0, &Bs[buf][wave * (BCH * 512)]);
        if constexpr (BCH == 2) glds16(gB1, &Bs[buf][wave * 1024 + 512]);
        gA0 += 32; gA1 += 32; gB0 += 32;
        if constexpr (BCH == 2) gB1 += 32;
    };

    stage(0);                             // tile 0 in flight into buf 0

    const int nk = K >> 5;
    int cur = 0;
    for (int kk = 0; kk < nk; ++kk) {
        if (kk + 1 < nk) {
            stage(cur ^ 1);               // issue next tile BEFORE waiting
            asm volatile("s_waitcnt vmcnt(%0)" :: "i"(NL) : "memory");
        } else {
            asm volatile("s_waitcnt vmcnt(0)" ::: "memory");
        }
        asm volatile("s_barrier" ::: "memory");   // raw: no compiler vmcnt(0) drain
        v8s af[4], bfr[NJ];
        #pragma unroll
        for (int i = 0; i < 4; ++i)
            af[i] = *(const v8s*)&As[cur][aoff[i]];
        #pragma unroll
        for (int j = 0; j < NJ; ++j)
            bfr[j] = *(const v8s*)&Bs[cur][boff[j]];
        #pragma unroll
        for (int i = 0; i < 4; ++i)
            #pragma unroll
            for (int j = 0; j < NJ; ++j)
                acc[i][j] = __builtin_amdgcn_mfma_f32_16x16x32_bf16(bfr[j], af[i], acc[i][j], 0, 0, 0);
        if (kk + 1 < nk)
            asm volatile("s_barrier" ::: "memory");  // all reads of buf[cur] done before restage
        cur ^= 1;
    }

    // packed epilogue: fixed m per lane, 4 consecutive n per acc
    #pragma unroll
    for (int i = 0; i < 4; ++i) {
        long m = tileM + wm + i * 16 + l16;
        #pragma unroll
        for (int j = 0; j < NJ; ++j) {
            long n0 = tileN + wn + j * 16 + quad * 4;
            float4 bi = *(const float4*)&bias[n0];
            const float* bip = (const float*)&bi;
            unsigned short pk[4];
            if (EPI == EPI_GELU_BF16) {
                #pragma unroll
                for (int r = 0; r < 4; ++r)
                    pk[r] = f2bf(fast_gelu(acc[i][j][r] + bip[r]));
            } else {
                ushort4 xr4 = *(const ushort4*)&xres[m * ldc + n0];
                const unsigned short* xp = (const unsigned short*)&xr4;
                #pragma unroll
                for (int r = 0; r < 4; ++r)
                    pk[r] = f2bf(acc[i][j][r] + bip[r] + bf2f(xp[r]));
            }
            *(ushort4*)&Cout[m * ldc + n0] = *(ushort4*)pk;
        }
    }
}

// ------- fused tanh-GEMM + class-GEMM, R2-structure K-loop, TM=128 -------
// (round-0 reg-staged structure; padded [40] rows are already conflict-light)
__global__ __launch_bounds__(256) void tanh_class_kernel(
        const unsigned short* __restrict__ A,
        const unsigned short* __restrict__ WT,
        const unsigned short* __restrict__ cls,
        unsigned short* __restrict__ uu) {
    __shared__ unsigned short As[128][40] __attribute__((aligned(16)));
    __shared__ unsigned short Bs[64][40] __attribute__((aligned(16)));
    __shared__ unsigned short P[128 * 72] __attribute__((aligned(16)));
    const int t = threadIdx.x;
    const int lane = t & 63, wave = t >> 6;
    const int quad = lane >> 4, l16 = lane & 15;
    const int wm = (wave >> 1) * 64, wn = (wave & 1) * 32;
    const long tileM = (long)blockIdx.x * 128;
    const int g = blockIdx.y;
    const int arow = t >> 2, acol = (t & 3) * 8;

    const unsigned short* BT = WT + g * 32768;
    v8s cf[2][2];
    #pragma unroll
    for (int ks = 0; ks < 2; ++ks)
        #pragma unroll
        for (int j = 0; j < 2; ++j)
            cf[ks][j] = *(const v8s*)&cls[g * 4096 + (wn + j * 16 + l16) * 64 + ks * 32 + quad * 8];

    const unsigned short* gA0 = A + (tileM + arow) * 512 + acol;
    const unsigned short* gA1 = gA0 + 64 * 512;
    const unsigned short* gB0 = BT + arow * 512 + acol;

    v4f acc[4][2] = {};
    uint4 a0, a1, b0;
    a0 = *(const uint4*)gA0; a1 = *(const uint4*)gA1; gA0 += 32; gA1 += 32;
    b0 = *(const uint4*)gB0; gB0 += 32;
    *(uint4*)&As[arow][acol] = a0;
    *(uint4*)&As[arow + 64][acol] = a1;
    *(uint4*)&Bs[arow][acol] = b0;

    for (int kk = 0; kk < 16; ++kk) {
        __syncthreads();
        const bool more = kk < 15;
        if (more) {
            a0 = *(const uint4*)gA0; a1 = *(const uint4*)gA1; gA0 += 32; gA1 += 32;
            b0 = *(const uint4*)gB0; gB0 += 32;
        }
        v8s af[4], bfr[2];
        #pragma unroll
        for (int i = 0; i < 4; ++i) af[i] = *(const v8s*)&As[wm + i * 16 + l16][quad * 8];
        #pragma unroll
        for (int j = 0; j < 2; ++j) bfr[j] = *(const v8s*)&Bs[wn + j * 16 + l16][quad * 8];
        #pragma unroll
        for (int i = 0; i < 4; ++i)
            #pragma unroll
            for (int j = 0; j < 2; ++j)
                acc[i][j] = __builtin_amdgcn_mfma_f32_16x16x32_bf16(bfr[j], af[i], acc[i][j], 0, 0, 0);
        __syncthreads();
        if (more) {
            *(uint4*)&As[arow][acol] = a0;
            *(uint4*)&As[arow + 64][acol] = a1;
            *(uint4*)&Bs[arow][acol] = b0;
        }
    }

    #pragma unroll
    for (int i = 0; i < 4; ++i) {
        int m = wm + i * 16 + l16;
        #pragma unroll
        for (int j = 0; j < 2; ++j) {
            int n0 = wn + j * 16 + quad * 4;
            unsigned short pk[4];
            #pragma unroll
            for (int r = 0; r < 4; ++r) pk[r] = f2bf(fast_tanh(acc[i][j][r]));
            *(ushort4*)&P[m * 72 + n0] = *(ushort4*)pk;
        }
    }
    __syncthreads();

    v4f acc2[4][2] = {};
    #pragma unroll
    for (int ks = 0; ks < 2; ++ks) {
        v8s paf[4];
        #pragma unroll
        for (int i = 0; i < 4; ++i)
            paf[i] = *(const v8s*)&P[(wm + i * 16 + l16) * 72 + ks * 32 + quad * 8];
        #pragma unroll
        for (int i = 0; i < 4; ++i)
            #pragma unroll
            for (int j = 0; j < 2; ++j)
                acc2[i][j] = __builtin_amdgcn_mfma_f32_16x16x32_bf16(cf[ks][j], paf[i], acc2[i][j], 0, 0, 0);
    }

    #pragma unroll
    for (int i = 0; i < 4; ++i) {
        long m = tileM + wm + i * 16 + l16;
        #pragma unroll
        for (int j = 0; j < 2; ++j) {
            int c0 = wn + j * 16 + quad * 4;
            unsigned short pk[4];
            #pragma unroll
            for (int r = 0; r < 4; ++r) pk[r] = f2bf(acc2[i][j][r]);
            *(ushort4*)&uu[m * 192 + g * 64 + c0] = *(ushort4*)pk;
        }
    }
}

// ------- exact ordered-triplet scan pass 1 -------
__global__ __launch_bounds__(64) void scan_part_kernel(const unsigned short* __restrict__ u,
                                                       float* __restrict__ part) {
    int b = blockIdx.x, seg = blockIdx.y;
    int c = threadIdx.x;
    int l0 = seg * 32;
    int l1 = l0 + 32; if (l1 > 2047) l1 = 2047;
    float sA = 0.f, sB = 0.f, sC = 0.f, T = 0.f, M = 0.f, U = 0.f;
    const unsigned short* base = u + ((size_t)b * LSEQ + l0) * 192 + c;
    for (int l = l0; l < l1; ++l) {
        float ua = bf2f(base[0]), ub = bf2f(base[64]), uc = bf2f(base[128]);
        base += 192;
        U += uc * T;
        M += uc * sB;
        T += ub * sA;
        sA += ua; sB += ub; sC += uc;
    }
    float* p = part + ((size_t)(b * 64 + seg)) * 384 + c;
    p[0] = sA; p[64] = sB; p[128] = sC; p[192] = T; p[256] = M; p[320] = U;
}

// ------- merged: segment combine + final LN + Wq GEMV -------
__global__ __launch_bounds__(64) void combine_final_kernel(const float* __restrict__ part,
        const unsigned short* __restrict__ x,
        const float* __restrict__ qw, const float* __restrict__ qb,
        const float* __restrict__ Wq, const float* __restrict__ bq,
        float* __restrict__ out, float inv_denom) {
    int b = blockIdx.x;
    int c = threadIdx.x;
    const float* p = part + (size_t)b * 64 * 384 + c;
    float A = p[0], B = p[64], Tt = p[192], Mt = p[256], Ut = p[320];
    for (int seg = 1; seg < 64; ++seg) {
        const float* q2 = p + seg * 384;
        float a2 = q2[0], b2 = q2[64], c2 = q2[128], t2 = q2[192], m2 = q2[256], u2 = q2[320];
        float Un = Ut + u2 + c2 * Tt + A * m2;
        float Tn = Tt + t2 + A * b2;
        float Mn = Mt + m2 + B * c2;
        A += a2; B += b2;
        Ut = Un; Tt = Tn; Mt = Mn;
    }
    __shared__ float q[512];
    __shared__ float mv[2];
    const unsigned short* xr = x + ((size_t)b * LSEQ + (LSEQ - 1)) * 512;
    float s1 = 0.f, s2 = 0.f;
    for (int i = c; i < 512; i += 64) { float v = bf2f(xr[i]); q[i] = v; s1 += v; s2 += v * v; }
    #pragma unroll
    for (int o = 32; o > 0; o >>= 1) { s1 += __shfl_down(s1, o); s2 += __shfl_down(s2, o); }
    if (c == 0) {
        float m = s1 * (1.0f / 512.0f);
        float var = s2 * (1.0f / 512.0f) - m * m;
        mv[0] = m; mv[1] = 1.0f / sqrtf(var + 1e-5f);
    }
    __syncthreads();
    float m = mv[0], r = mv[1];
    for (int i = c; i < 512; i += 64) q[i] = (q[i] - m) * r * qw[i] + qb[i];
    __syncthreads();
    float acc = 0.f;
    for (int d = 0; d < 512; ++d) acc += q[d] * Wq[d * 64 + c];
    out[b * 64 + c] = Ut * inv_denom + acc + bq[c];
}

extern "C" void kernel_launch(void* const* d_in, const int* in_sizes, int n_in,
                              void* d_out, int out_size, void* d_ws, size_t ws_size,
                              hipStream_t stream) {
    const int*   token_ids   = (const int*)d_in[0];
    const float* tok_emb     = (const float*)d_in[1];
    const float* pos_emb     = (const float*)d_in[2];
    const float* stem_ln_w   = (const float*)d_in[3];
    const float* stem_ln_b   = (const float*)d_in[4];
    const float* stem_w1     = (const float*)d_in[5];
    const float* stem_b1     = (const float*)d_in[6];
    const float* stem_w2     = (const float*)d_in[7];
    const float* stem_b2     = (const float*)d_in[8];
    const float* role_ln_w   = (const float*)d_in[9];
    const float* role_ln_b   = (const float*)d_in[10];
    const float* Wa          = (const float*)d_in[11];
    const float* Wb          = (const float*)d_in[12];
    const float* Wc          = (const float*)d_in[13];
    const float* class_a     = (const float*)d_in[14];
    const float* class_b     = (const float*)d_in[15];
    const float* class_c     = (const float*)d_in[16];
    const float* query_ln_w  = (const float*)d_in[17];
    const float* query_ln_b  = (const float*)d_in[18];
    const float* Wq          = (const float*)d_in[19];
    const float* bq          = (const float*)d_in[20];
    float* out = (float*)d_out;

    char* wsb = (char*)d_ws;
    unsigned short* x    = (unsigned short*)(wsb);              // 16,777,216
    unsigned short* hl   = (unsigned short*)(wsb + 16777216);   // 16,777,216
    unsigned short* Hb   = (unsigned short*)(wsb + 33554432);   // 33,554,432
    unsigned short* uu   = (unsigned short*)(wsb + 67108864);   // 6,291,456
    float* part          = (float*)(wsb + 73400320);            // 786,432
    unsigned short* w1T  = (unsigned short*)(wsb + 74188800);   // 2,097,152
    unsigned short* w2T  = (unsigned short*)(wsb + 76285952);   // 2,097,152
    unsigned short* wabcT= (unsigned short*)(wsb + 78383104);   // 196,608
    unsigned short* clsb = (unsigned short*)(wsb + 78579712);   // 24,576

    setup_kernel<<<6243, 256, 0, stream>>>(token_ids, tok_emb, pos_emb,
        stem_ln_w, stem_ln_b, x, hl,
        stem_w1, stem_w2, Wa, Wb, Wc, class_a, class_b, class_c,
        w1T, w2T, wabcT, clsb);

    for (int i = 0; i < 2; ++i) {
        if (i > 0)
            ln_kernel<<<NROWS / 4, 256, 0, stream>>>(x, stem_ln_w + 512, stem_ln_b + 512, hl);
        gemm_swz<EPI_GELU_BF16, 128><<<dim3(128, 8), 256, 0, stream>>>(
            hl, 512, w1T + i * 524288, 512, stem_b1 + i * 1024, nullptr, Hb, 1024, 512);
        gemm_swz<EPI_RES_BF16, 64><<<dim3(128, 8), 256, 0, stream>>>(
            Hb, 1024, w2T + i * 524288, 1024, stem_b2 + i * 512, x, x, 512, 1024);
    }

    ln_kernel<<<NROWS / 4, 256, 0, stream>>>(x, role_ln_w, role_ln_b, hl);

    tanh_class_kernel<<<dim3(128, 3), 256, 0, stream>>>(hl, wabcT, clsb, uu);

    scan_part_kernel<<<dim3(NB, 64), 64, 0, stream>>>(uu, part);

    float inv_denom = (float)(6.0 / (2047.0 * 2046.0 * 2045.0));
    combine_final_kernel<<<NB, 64, 0, stream>>>(part, x, query_ln_w, query_ln_b,
                                                Wq, bq, out, inv_denom);
}

// Round 5
// 327.058 us; speedup vs baseline: 1.0876x; 1.0308x over previous
//
#include <hip/hip_runtime.h>

#define NROWS 16384   // B*L
#define LSEQ  2048
#define NB    8

typedef short v8s __attribute__((ext_vector_type(8)));
typedef float v4f __attribute__((ext_vector_type(4)));

__device__ __forceinline__ unsigned short f2bf(float f) {
    unsigned int u = __float_as_uint(f);
    return (unsigned short)((u + 0x7fffu + ((u >> 16) & 1u)) >> 16);
}
__device__ __forceinline__ float bf2f(unsigned short u) {
    return __uint_as_float(((unsigned int)u) << 16);
}

// async global->LDS, 16B per lane; LDS dest is wave-uniform base + lane*16
__device__ __forceinline__ void glds16(const void* g, void* l) {
    __builtin_amdgcn_global_load_lds(
        (__attribute__((address_space(1))) void*)g,
        (__attribute__((address_space(3))) void*)l,
        16, 0, 0);
}

// fast exact-GELU: Abramowitz-Stegun 5-term erf, |err|<1.5e-7
__device__ __forceinline__ float fast_gelu(float v) {
    float z = fabsf(v) * 0.70710678118654752f;
    float t = __builtin_amdgcn_rcpf(1.0f + 0.3275911f * z);
    float poly = t * (0.254829592f + t * (-0.284496736f + t * (1.421413741f +
                 t * (-1.453152027f + t * 1.061405429f))));
    float erfz = 1.0f - poly * __expf(-z * z);
    float er = copysignf(erfz, v);
    return 0.5f * v * (1.0f + er);
}
__device__ __forceinline__ float fast_tanh(float y) {
    float e = __expf(2.0f * y);
    return (e - 1.0f) * __builtin_amdgcn_rcpf(e + 1.0f);
}

// XCD row-swizzle: block b (of 4096, 4 rows each) -> rows of 128-row tile T with
// T%8 == b%8, so the producer's XCD matches the GEMM reader's XCD (= (m>>7)%8).
__device__ __forceinline__ long swizzled_row(int b, int wave) {
    int T = (b & 7) + (((b >> 3) & 15) << 3);   // 0..127, T%8 == b%8
    int chunk = b >> 7;                          // 0..31
    return (long)T * 128 + chunk * 4 + wave;
}

// ------- merged setup: embed (blocks 0..4095, XCD-swizzled) | weight transposes
//         (4096..6239) | class converts (6240..6242); embed also emits LN0(hl) -------
__global__ __launch_bounds__(256) void setup_kernel(
        const int* __restrict__ ids,
        const float* __restrict__ tok, const float* __restrict__ pos,
        const float* __restrict__ g0, const float* __restrict__ b0,
        unsigned short* __restrict__ x, unsigned short* __restrict__ hl,
        const float* __restrict__ w1, const float* __restrict__ w2,
        const float* __restrict__ wa, const float* __restrict__ wb, const float* __restrict__ wc,
        const float* __restrict__ ca, const float* __restrict__ cb, const float* __restrict__ cc,
        unsigned short* __restrict__ w1T, unsigned short* __restrict__ w2T,
        unsigned short* __restrict__ wabcT, unsigned short* __restrict__ clsb) {
    int blk = blockIdx.x;
    int t = threadIdx.x;
    if (blk < 4096) {
        int wave = t >> 6, lane = t & 63;
        long row = swizzled_row(blk, wave);
        int l = (int)(row & (LSEQ - 1));
        int id = ids[row];
        int d = lane * 8;
        float4 t0 = *(const float4*)(tok + (size_t)id * 512 + d);
        float4 t1 = *(const float4*)(tok + (size_t)id * 512 + d + 4);
        float4 p0 = *(const float4*)(pos + (size_t)l * 512 + d);
        float4 p1 = *(const float4*)(pos + (size_t)l * 512 + d + 4);
        float a[8] = {t0.x + p0.x, t0.y + p0.y, t0.z + p0.z, t0.w + p0.w,
                      t1.x + p1.x, t1.y + p1.y, t1.z + p1.z, t1.w + p1.w};
        unsigned int xp[4];
        #pragma unroll
        for (int i = 0; i < 4; ++i)
            xp[i] = (unsigned int)f2bf(a[2 * i]) | ((unsigned int)f2bf(a[2 * i + 1]) << 16);
        *(uint4*)(x + row * 512 + d) = *(uint4*)xp;
        float s = 0.f, s2 = 0.f;
        #pragma unroll
        for (int i = 0; i < 8; ++i) { s += a[i]; s2 += a[i] * a[i]; }
        #pragma unroll
        for (int o = 32; o > 0; o >>= 1) { s += __shfl_down(s, o); s2 += __shfl_down(s2, o); }
        s = __shfl(s, 0); s2 = __shfl(s2, 0);
        float m = s * (1.0f / 512.0f);
        float rinv = 1.0f / sqrtf(s2 * (1.0f / 512.0f) - m * m + 1e-5f);
        float4 ga = *(const float4*)(g0 + d), gb = *(const float4*)(g0 + d + 4);
        float4 ba = *(const float4*)(b0 + d), bb2 = *(const float4*)(b0 + d + 4);
        float gg[8] = {ga.x, ga.y, ga.z, ga.w, gb.x, gb.y, gb.z, gb.w};
        float bb[8] = {ba.x, ba.y, ba.z, ba.w, bb2.x, bb2.y, bb2.z, bb2.w};
        unsigned int hp[4];
        #pragma unroll
        for (int i = 0; i < 4; ++i) {
            unsigned short lo = f2bf((a[2 * i]     - m) * rinv * gg[2 * i]     + bb[2 * i]);
            unsigned short hi = f2bf((a[2 * i + 1] - m) * rinv * gg[2 * i + 1] + bb[2 * i + 1]);
            hp[i] = (unsigned int)lo | ((unsigned int)hi << 16);
        }
        *(uint4*)(hl + row * 512 + d) = *(uint4*)hp;
    } else if (blk < 6240) {
        int id = blk - 4096;
        int tx = t & 31, ty = t >> 5;
        const float* in; unsigned short* out; int R, C, bx, by, ldo;
        if (id < 1024) {
            int l = id >> 9, r = id & 511;
            in = w1 + l * 524288; out = w1T + l * 524288;
            R = 512; C = 1024; bx = r & 31; by = r >> 5; ldo = 512;
        } else if (id < 2048) {
            int l = (id - 1024) >> 9, r = (id - 1024) & 511;
            in = w2 + l * 524288; out = w2T + l * 524288;
            R = 1024; C = 512; bx = r & 15; by = r >> 4; ldo = 1024;
        } else {
            int g = (id - 2048) >> 5, r = (id - 2048) & 31;
            in = (g == 0) ? wa : (g == 1) ? wb : wc;
            out = wabcT + g * 32768;
            R = 512; C = 64; bx = r & 1; by = r >> 1; ldo = 512;
        }
        __shared__ unsigned short tile[32][33];
        int c0 = bx * 32, r0 = by * 32;
        for (int i = ty; i < 32; i += 8) {
            int r = r0 + i, c = c0 + tx;
            tile[i][tx] = (r < R && c < C) ? f2bf(in[(size_t)r * C + c]) : (unsigned short)0;
        }
        __syncthreads();
        for (int i = ty; i < 32; i += 8) {
            int c = c0 + i, r = r0 + tx;
            if (r < R && c < C) out[(size_t)c * ldo + r] = tile[tx][i];
        }
    } else {
        int g = blk - 6240;
        const float* src = (g == 0) ? ca : (g == 1) ? cb : cc;
        unsigned short* dst = clsb + g * 4096;
        for (int i = t; i < 4096; i += 256) dst[i] = f2bf(src[i]);
    }
}

// ------- LayerNorm, one wave per row, XCD-swizzled block->row mapping -------
__global__ __launch_bounds__(256) void ln_kernel(const unsigned short* __restrict__ x,
        const float* __restrict__ g, const float* __restrict__ b,
        unsigned short* __restrict__ out) {
    int wave = threadIdx.x >> 6, lane = threadIdx.x & 63;
    long row = swizzled_row(blockIdx.x, wave);
    int d = lane * 8;
    uint4 xp = *(const uint4*)(x + row * 512 + d);
    const unsigned int* xw = (const unsigned int*)&xp;
    float a[8];
    #pragma unroll
    for (int i = 0; i < 4; ++i) {
        a[2 * i]     = bf2f((unsigned short)(xw[i] & 0xffff));
        a[2 * i + 1] = bf2f((unsigned short)(xw[i] >> 16));
    }
    float s = 0.f, s2 = 0.f;
    #pragma unroll
    for (int i = 0; i < 8; ++i) { s += a[i]; s2 += a[i] * a[i]; }
    #pragma unroll
    for (int o = 32; o > 0; o >>= 1) { s += __shfl_down(s, o); s2 += __shfl_down(s2, o); }
    s = __shfl(s, 0); s2 = __shfl(s2, 0);
    float m = s * (1.0f / 512.0f);
    float rinv = 1.0f / sqrtf(s2 * (1.0f / 512.0f) - m * m + 1e-5f);
    float4 g0 = *(const float4*)(g + d), g1 = *(const float4*)(g + d + 4);
    float4 b0 = *(const float4*)(b + d), b1 = *(const float4*)(b + d + 4);
    float gg[8] = {g0.x, g0.y, g0.z, g0.w, g1.x, g1.y, g1.z, g1.w};
    float bb[8] = {b0.x, b0.y, b0.z, b0.w, b1.x, b1.y, b1.z, b1.w};
    unsigned int hp[4];
    #pragma unroll
    for (int i = 0; i < 4; ++i) {
        unsigned short lo = f2bf((a[2 * i]     - m) * rinv * gg[2 * i]     + bb[2 * i]);
        unsigned short hi = f2bf((a[2 * i + 1] - m) * rinv * gg[2 * i + 1] + bb[2 * i + 1]);
        hp[i] = (unsigned int)lo | ((unsigned int)hi << 16);
    }
    *(uint4*)(out + row * 512 + d) = *(uint4*)hp;
}

// ------- 8-phase 256-row MFMA GEMM (m201 template, plain HIP) -------
// BM=256, BK=64, 512 thr = 8 waves (2M x 4N); per-wave out 128 x BN/4.
// Per K-tile: 4 phases = {row-half x col-half} x K64, each staging one future
// half-tile; counted vmcnt once per K-tile before the phase-end barrier.
// LDS linear for glds16; bank swizzle slot^=row&7 folded into SOURCE addr and
// READ offsets (involution round-trips -> canonical fragment data).
#define EPI_GELU_BF16  0
#define EPI_RES_BF16   1

template <int EPI, int BN>
__global__ __launch_bounds__(512, 1) void gemm_8p(
        const unsigned short* __restrict__ A, int lda,
        const unsigned short* __restrict__ BT, int ldb,
        const float* __restrict__ bias,
        const unsigned short* __restrict__ xres,
        unsigned short* __restrict__ Cout, int ldc, int K) {
    constexpr int NFC = BN / 64;        // frag-cols per wave: 4 / 2
    constexpr int FCH = NFC / 2;        // frag-cols per col-half: 2 / 1
    constexpr int NLB = BN / 128;       // glds per wave per B-half: 2 / 1
    constexpr int BH  = BN / 2;         // rows per B-half: 128 / 64
    __shared__ unsigned short Ab[2][2][128 * 64] __attribute__((aligned(16)));
    __shared__ unsigned short Bb[2][2][BH * 64] __attribute__((aligned(16)));
    const int t = threadIdx.x;
    const int lane = t & 63, w = t >> 6;
    const int quad = lane >> 4, l16 = lane & 15;
    const int wmh = w >> 2;             // wave A-half (0/1)
    const int wn  = w & 3;
    const int bhalf = wn >> 1, bbase = (wn & 1) * (BN / 4);
    const long tileM = (long)blockIdx.x * 256;
    const long tileN = (long)blockIdx.y * BN;

    // staging lane geometry: LDS dest linear; source col-chunk = (lane&7)^(lane>>3)
    const int rl = lane >> 3;
    const int cl = ((lane & 7) ^ rl) * 8;

    const unsigned short* pa[2][2];
    #pragma unroll
    for (int h = 0; h < 2; ++h)
        #pragma unroll
        for (int q = 0; q < 2; ++q)
            pa[h][q] = A + (tileM + h * 128 + w * 16 + q * 8 + rl) * (size_t)lda + cl;
    const unsigned short* pb[2][2];
    #pragma unroll
    for (int h = 0; h < 2; ++h) {
        if constexpr (NLB == 2) {
            #pragma unroll
            for (int q = 0; q < 2; ++q)
                pb[h][q] = BT + (tileN + h * BH + w * 16 + q * 8 + rl) * (size_t)ldb + cl;
        } else {
            pb[h][0] = BT + (tileN + h * BH + w * 8 + rl) * (size_t)ldb + cl;
        }
    }
    int kA = 0, kB = 0;

    auto stageA = [&](int buf, int h) {
        glds16(pa[h][0] + kA, &Ab[buf][h][(w * 2 + 0) * 512]);
        glds16(pa[h][1] + kA, &Ab[buf][h][(w * 2 + 1) * 512]);
    };
    auto stageB = [&](int buf, int h) {
        if constexpr (NLB == 2) {
            glds16(pb[h][0] + kB, &Bb[buf][h][(w * 2 + 0) * 512]);
            glds16(pb[h][1] + kB, &Bb[buf][h][(w * 2 + 1) * 512]);
        } else {
            glds16(pb[h][0] + kB, &Bb[buf][h][w * 512]);
        }
    };

    // LDS read k-slot offsets (shorts): canonical slot ^ (l16&7)
    const int xl = l16 & 7;
    const int ak0 = l16 * 64 + (((quad    ) ^ xl) * 8);
    const int ak1 = l16 * 64 + (((quad + 4) ^ xl) * 8);

    // prologue: A(0), B(0), B(1)  (B(1) issued LAST for the counted wait)
    stageA(0, 0); stageA(0, 1); kA = 64;
    stageB(0, 0); stageB(0, 1); kB = 64;
    stageB(1, 0); stageB(1, 1); kB = 128;

    v4f acc[8][NFC] = {};
    const int nt = K >> 6;

    asm volatile("s_waitcnt vmcnt(%0)" :: "i"(2 * NLB) : "memory");
    __builtin_amdgcn_s_barrier();

    for (int tt = 0; tt < nt; ++tt) {
        const int bi = tt & 1;
        const unsigned short* Ah = &Ab[bi][wmh][0];
        const unsigned short* Bh = &Bb[bi][bhalf][bbase * 64];
        v8s af[4][2], bf[NFC][2];

        // ---- ph0: read A-lo + B-lo; stage A0(t+1) ----
        #pragma unroll
        for (int fr = 0; fr < 4; ++fr) {
            af[fr][0] = *(const v8s*)(Ah + fr * 1024 + ak0);
            af[fr][1] = *(const v8s*)(Ah + fr * 1024 + ak1);
        }
        #pragma unroll
        for (int fc = 0; fc < FCH; ++fc) {
            bf[fc][0] = *(const v8s*)(Bh + fc * 1024 + ak0);
            bf[fc][1] = *(const v8s*)(Bh + fc * 1024 + ak1);
        }
        if (tt + 1 < nt) stageA(bi ^ 1, 0);
        __builtin_amdgcn_s_barrier();
        asm volatile("s_waitcnt lgkmcnt(0)" ::: "memory");
        __builtin_amdgcn_s_setprio(1);
        #pragma unroll
        for (int fr = 0; fr < 4; ++fr)
            #pragma unroll
            for (int fc = 0; fc < FCH; ++fc) {
                acc[fr][fc] = __builtin_amdgcn_mfma_f32_16x16x32_bf16(bf[fc][0], af[fr][0], acc[fr][fc], 0, 0, 0);
                acc[fr][fc] = __builtin_amdgcn_mfma_f32_16x16x32_bf16(bf[fc][1], af[fr][1], acc[fr][fc], 0, 0, 0);
            }
        __builtin_amdgcn_s_setprio(0);
        __builtin_amdgcn_s_barrier();

        // ---- ph1: read B-hi; stage A1(t+1) ----
        #pragma unroll
        for (int fc = FCH; fc < NFC; ++fc) {
            bf[fc][0] = *(const v8s*)(Bh + fc * 1024 + ak0);
            bf[fc][1] = *(const v8s*)(Bh + fc * 1024 + ak1);
        }
        if (tt + 1 < nt) stageA(bi ^ 1, 1);
        kA += 64;
        __builtin_amdgcn_s_barrier();
        asm volatile("s_waitcnt lgkmcnt(0)" ::: "memory");
        __builtin_amdgcn_s_setprio(1);
        #pragma unroll
        for (int fr = 0; fr < 4; ++fr)
            #pragma unroll
            for (int fc = FCH; fc < NFC; ++fc) {
                acc[fr][fc] = __builtin_amdgcn_mfma_f32_16x16x32_bf16(bf[fc][0], af[fr][0], acc[fr][fc], 0, 0, 0);
                acc[fr][fc] = __builtin_amdgcn_mfma_f32_16x16x32_bf16(bf[fc][1], af[fr][1], acc[fr][fc], 0, 0, 0);
            }
        __builtin_amdgcn_s_setprio(0);
        __builtin_amdgcn_s_barrier();

        // ---- ph2: read A-hi; stage B0(t+2) (B(t) reads finished in ph1) ----
        #pragma unroll
        for (int fr = 0; fr < 4; ++fr) {
            af[fr][0] = *(const v8s*)(Ah + (fr + 4) * 1024 + ak0);
            af[fr][1] = *(const v8s*)(Ah + (fr + 4) * 1024 + ak1);
        }
        if (tt + 2 < nt) stageB(bi, 0);
        __builtin_amdgcn_s_barrier();
        asm volatile("s_waitcnt lgkmcnt(0)" ::: "memory");
        __builtin_amdgcn_s_setprio(1);
        #pragma unroll
        for (int fr = 0; fr < 4; ++fr)
            #pragma unroll
            for (int fc = 0; fc < FCH; ++fc) {
                acc[fr + 4][fc] = __builtin_amdgcn_mfma_f32_16x16x32_bf16(bf[fc][0], af[fr][0], acc[fr + 4][fc], 0, 0, 0);
                acc[fr + 4][fc] = __builtin_amdgcn_mfma_f32_16x16x32_bf16(bf[fc][1], af[fr][1], acc[fr + 4][fc], 0, 0, 0);
            }
        __builtin_amdgcn_s_setprio(0);
        __builtin_amdgcn_s_barrier();

        // ---- ph3: stage B1(t+2); counted vmcnt for tile t+1; MFMA A-hi x B-hi ----
        if (tt + 2 < nt) stageB(bi, 1);
        kB += 64;
        if (tt + 2 < nt)
            asm volatile("s_waitcnt vmcnt(%0)" :: "i"(2 * NLB) : "memory");
        else if (tt + 1 < nt)
            asm volatile("s_waitcnt vmcnt(0)" ::: "memory");
        __builtin_amdgcn_s_barrier();
        __builtin_amdgcn_s_setprio(1);
        #pragma unroll
        for (int fr = 0; fr < 4; ++fr)
            #pragma unroll
            for (int fc = FCH; fc < NFC; ++fc) {
                acc[fr + 4][fc] = __builtin_amdgcn_mfma_f32_16x16x32_bf16(bf[fc][0], af[fr][0], acc[fr + 4][fc], 0, 0, 0);
                acc[fr + 4][fc] = __builtin_amdgcn_mfma_f32_16x16x32_bf16(bf[fc][1], af[fr][1], acc[fr + 4][fc], 0, 0, 0);
            }
        __builtin_amdgcn_s_setprio(0);
        __builtin_amdgcn_s_barrier();
    }

    // packed epilogue
    #pragma unroll
    for (int fr = 0; fr < 8; ++fr) {
        long m = tileM + wmh * 128 + fr * 16 + l16;
        #pragma unroll
        for (int fc = 0; fc < NFC; ++fc) {
            long n0 = tileN + wn * (BN / 4) + fc * 16 + quad * 4;
            float4 bi4 = *(const float4*)&bias[n0];
            const float* bip = (const float*)&bi4;
            unsigned short pk[4];
            if (EPI == EPI_GELU_BF16) {
                #pragma unroll
                for (int r = 0; r < 4; ++r)
                    pk[r] = f2bf(fast_gelu(acc[fr][fc][r] + bip[r]));
            } else {
                ushort4 xr4 = *(const ushort4*)&xres[m * ldc + n0];
                const unsigned short* xp = (const unsigned short*)&xr4;
                #pragma unroll
                for (int r = 0; r < 4; ++r)
                    pk[r] = f2bf(acc[fr][fc][r] + bip[r] + bf2f(xp[r]));
            }
            *(ushort4*)&Cout[m * ldc + n0] = *(ushort4*)pk;
        }
    }
}

// ------- fused tanh-GEMM + class-GEMM, R2-structure K-loop, TM=128 -------
__global__ __launch_bounds__(256) void tanh_class_kernel(
        const unsigned short* __restrict__ A,
        const unsigned short* __restrict__ WT,
        const unsigned short* __restrict__ cls,
        unsigned short* __restrict__ uu) {
    __shared__ unsigned short As[128][40] __attribute__((aligned(16)));
    __shared__ unsigned short Bs[64][40] __attribute__((aligned(16)));
    __shared__ unsigned short P[128 * 72] __attribute__((aligned(16)));
    const int t = threadIdx.x;
    const int lane = t & 63, wave = t >> 6;
    const int quad = lane >> 4, l16 = lane & 15;
    const int wm = (wave >> 1) * 64, wn = (wave & 1) * 32;
    const long tileM = (long)blockIdx.x * 128;
    const int g = blockIdx.y;
    const int arow = t >> 2, acol = (t & 3) * 8;

    const unsigned short* BT = WT + g * 32768;
    v8s cf[2][2];
    #pragma unroll
    for (int ks = 0; ks < 2; ++ks)
        #pragma unroll
        for (int j = 0; j < 2; ++j)
            cf[ks][j] = *(const v8s*)&cls[g * 4096 + (wn + j * 16 + l16) * 64 + ks * 32 + quad * 8];

    const unsigned short* gA0 = A + (tileM + arow) * 512 + acol;
    const unsigned short* gA1 = gA0 + 64 * 512;
    const unsigned short* gB0 = BT + arow * 512 + acol;

    v4f acc[4][2] = {};
    uint4 a0, a1, b0;
    a0 = *(const uint4*)gA0; a1 = *(const uint4*)gA1; gA0 += 32; gA1 += 32;
    b0 = *(const uint4*)gB0; gB0 += 32;
    *(uint4*)&As[arow][acol] = a0;
    *(uint4*)&As[arow + 64][acol] = a1;
    *(uint4*)&Bs[arow][acol] = b0;

    for (int kk = 0; kk < 16; ++kk) {
        __syncthreads();
        const bool more = kk < 15;
        if (more) {
            a0 = *(const uint4*)gA0; a1 = *(const uint4*)gA1; gA0 += 32; gA1 += 32;
            b0 = *(const uint4*)gB0; gB0 += 32;
        }
        v8s af[4], bfr[2];
        #pragma unroll
        for (int i = 0; i < 4; ++i) af[i] = *(const v8s*)&As[wm + i * 16 + l16][quad * 8];
        #pragma unroll
        for (int j = 0; j < 2; ++j) bfr[j] = *(const v8s*)&Bs[wn + j * 16 + l16][quad * 8];
        #pragma unroll
        for (int i = 0; i < 4; ++i)
            #pragma unroll
            for (int j = 0; j < 2; ++j)
                acc[i][j] = __builtin_amdgcn_mfma_f32_16x16x32_bf16(bfr[j], af[i], acc[i][j], 0, 0, 0);
        __syncthreads();
        if (more) {
            *(uint4*)&As[arow][acol] = a0;
            *(uint4*)&As[arow + 64][acol] = a1;
            *(uint4*)&Bs[arow][acol] = b0;
        }
    }

    #pragma unroll
    for (int i = 0; i < 4; ++i) {
        int m = wm + i * 16 + l16;
        #pragma unroll
        for (int j = 0; j < 2; ++j) {
            int n0 = wn + j * 16 + quad * 4;
            unsigned short pk[4];
            #pragma unroll
            for (int r = 0; r < 4; ++r) pk[r] = f2bf(fast_tanh(acc[i][j][r]));
            *(ushort4*)&P[m * 72 + n0] = *(ushort4*)pk;
        }
    }
    __syncthreads();

    v4f acc2[4][2] = {};
    #pragma unroll
    for (int ks = 0; ks < 2; ++ks) {
        v8s paf[4];
        #pragma unroll
        for (int i = 0; i < 4; ++i)
            paf[i] = *(const v8s*)&P[(wm + i * 16 + l16) * 72 + ks * 32 + quad * 8];
        #pragma unroll
        for (int i = 0; i < 4; ++i)
            #pragma unroll
            for (int j = 0; j < 2; ++j)
                acc2[i][j] = __builtin_amdgcn_mfma_f32_16x16x32_bf16(cf[ks][j], paf[i], acc2[i][j], 0, 0, 0);
    }

    #pragma unroll
    for (int i = 0; i < 4; ++i) {
        long m = tileM + wm + i * 16 + l16;
        #pragma unroll
        for (int j = 0; j < 2; ++j) {
            int c0 = wn + j * 16 + quad * 4;
            unsigned short pk[4];
            #pragma unroll
            for (int r = 0; r < 4; ++r) pk[r] = f2bf(acc2[i][j][r]);
            *(ushort4*)&uu[m * 192 + g * 64 + c0] = *(ushort4*)pk;
        }
    }
}

// ------- exact ordered-triplet scan pass 1 -------
__global__ __launch_bounds__(64) void scan_part_kernel(const unsigned short* __restrict__ u,
                                                       float* __restrict__ part) {
    int b = blockIdx.x, seg = blockIdx.y;
    int c = threadIdx.x;
    int l0 = seg * 32;
    int l1 = l0 + 32; if (l1 > 2047) l1 = 2047;
    float sA = 0.f, sB = 0.f, sC = 0.f, T = 0.f, M = 0.f, U = 0.f;
    const unsigned short* base = u + ((size_t)b * LSEQ + l0) * 192 + c;
    for (int l = l0; l < l1; ++l) {
        float ua = bf2f(base[0]), ub = bf2f(base[64]), uc = bf2f(base[128]);
        base += 192;
        U += uc * T;
        M += uc * sB;
        T += ub * sA;
        sA += ua; sB += ub; sC += uc;
    }
    float* p = part + ((size_t)(b * 64 + seg)) * 384 + c;
    p[0] = sA; p[64] = sB; p[128] = sC; p[192] = T; p[256] = M; p[320] = U;
}

// ------- merged: segment combine + final LN + Wq GEMV -------
__global__ __launch_bounds__(64) void combine_final_kernel(const float* __restrict__ part,
        const unsigned short* __restrict__ x,
        const float* __restrict__ qw, const float* __restrict__ qb,
        const float* __restrict__ Wq, const float* __restrict__ bq,
        float* __restrict__ out, float inv_denom) {
    int b = blockIdx.x;
    int c = threadIdx.x;
    const float* p = part + (size_t)b * 64 * 384 + c;
    float A = p[0], B = p[64], Tt = p[192], Mt = p[256], Ut = p[320];
    for (int seg = 1; seg < 64; ++seg) {
        const float* q2 = p + seg * 384;
        float a2 = q2[0], b2 = q2[64], c2 = q2[128], t2 = q2[192], m2 = q2[256], u2 = q2[320];
        float Un = Ut + u2 + c2 * Tt + A * m2;
        float Tn = Tt + t2 + A * b2;
        float Mn = Mt + m2 + B * c2;
        A += a2; B += b2;
        Ut = Un; Tt = Tn; Mt = Mn;
    }
    __shared__ float q[512];
    __shared__ float mv[2];
    const unsigned short* xr = x + ((size_t)b * LSEQ + (LSEQ - 1)) * 512;
    float s1 = 0.f, s2 = 0.f;
    for (int i = c; i < 512; i += 64) { float v = bf2f(xr[i]); q[i] = v; s1 += v; s2 += v * v; }
    #pragma unroll
    for (int o = 32; o > 0; o >>= 1) { s1 += __shfl_down(s1, o); s2 += __shfl_down(s2, o); }
    if (c == 0) {
        float m = s1 * (1.0f / 512.0f);
        float var = s2 * (1.0f / 512.0f) - m * m;
        mv[0] = m; mv[1] = 1.0f / sqrtf(var + 1e-5f);
    }
    __syncthreads();
    float m = mv[0], r = mv[1];
    for (int i = c; i < 512; i += 64) q[i] = (q[i] - m) * r * qw[i] + qb[i];
    __syncthreads();
    float acc = 0.f;
    for (int d = 0; d < 512; ++d) acc += q[d] * Wq[d * 64 + c];
    out[b * 64 + c] = Ut * inv_denom + acc + bq[c];
}

extern "C" void kernel_launch(void* const* d_in, const int* in_sizes, int n_in,
                              void* d_out, int out_size, void* d_ws, size_t ws_size,
                              hipStream_t stream) {
    const int*   token_ids   = (const int*)d_in[0];
    const float* tok_emb     = (const float*)d_in[1];
    const float* pos_emb     = (const float*)d_in[2];
    const float* stem_ln_w   = (const float*)d_in[3];
    const float* stem_ln_b   = (const float*)d_in[4];
    const float* stem_w1     = (const float*)d_in[5];
    const float* stem_b1     = (const float*)d_in[6];
    const float* stem_w2     = (const float*)d_in[7];
    const float* stem_b2     = (const float*)d_in[8];
    const float* role_ln_w   = (const float*)d_in[9];
    const float* role_ln_b   = (const float*)d_in[10];
    const float* Wa          = (const float*)d_in[11];
    const float* Wb          = (const float*)d_in[12];
    const float* Wc          = (const float*)d_in[13];
    const float* class_a     = (const float*)d_in[14];
    const float* class_b     = (const float*)d_in[15];
    const float* class_c     = (const float*)d_in[16];
    const float* query_ln_w  = (const float*)d_in[17];
    const float* query_ln_b  = (const float*)d_in[18];
    const float* Wq          = (const float*)d_in[19];
    const float* bq          = (const float*)d_in[20];
    float* out = (float*)d_out;

    char* wsb = (char*)d_ws;
    unsigned short* x    = (unsigned short*)(wsb);              // 16,777,216
    unsigned short* hl   = (unsigned short*)(wsb + 16777216);   // 16,777,216
    unsigned short* Hb   = (unsigned short*)(wsb + 33554432);   // 33,554,432
    unsigned short* uu   = (unsigned short*)(wsb + 67108864);   // 6,291,456
    float* part          = (float*)(wsb + 73400320);            // 786,432
    unsigned short* w1T  = (unsigned short*)(wsb + 74188800);   // 2,097,152
    unsigned short* w2T  = (unsigned short*)(wsb + 76285952);   // 2,097,152
    unsigned short* wabcT= (unsigned short*)(wsb + 78383104);   // 196,608
    unsigned short* clsb = (unsigned short*)(wsb + 78579712);   // 24,576

    setup_kernel<<<6243, 256, 0, stream>>>(token_ids, tok_emb, pos_emb,
        stem_ln_w, stem_ln_b, x, hl,
        stem_w1, stem_w2, Wa, Wb, Wc, class_a, class_b, class_c,
        w1T, w2T, wabcT, clsb);

    for (int i = 0; i < 2; ++i) {
        if (i > 0)
            ln_kernel<<<NROWS / 4, 256, 0, stream>>>(x, stem_ln_w + 512, stem_ln_b + 512, hl);
        gemm_8p<EPI_GELU_BF16, 256><<<dim3(64, 4), 512, 0, stream>>>(
            hl, 512, w1T + i * 524288, 512, stem_b1 + i * 1024, nullptr, Hb, 1024, 512);
        gemm_8p<EPI_RES_BF16, 128><<<dim3(64, 4), 512, 0, stream>>>(
            Hb, 1024, w2T + i * 524288, 1024, stem_b2 + i * 512, x, x, 512, 1024);
    }

    ln_kernel<<<NROWS / 4, 256, 0, stream>>>(x, role_ln_w, role_ln_b, hl);

    tanh_class_kernel<<<dim3(128, 3), 256, 0, stream>>>(hl, wabcT, clsb, uu);

    scan_part_kernel<<<dim3(NB, 64), 64, 0, stream>>>(uu, part);

    float inv_denom = (float)(6.0 / (2047.0 * 2046.0 * 2045.0));
    combine_final_kernel<<<NB, 64, 0, stream>>>(part, x, query_ln_w, query_ln_b,
                                                Wq, bq, out, inv_denom);
}